// Round 1
// 457.098 us; speedup vs baseline: 1.1011x; 1.1011x over previous
//
#include <hip/hip_runtime.h>
#include <hip/hip_bf16.h>

// LiteMSA pipeline, MI355X gfx950.
// B=16, Cin=256, Cqkv=768, H=W=64 (P=4096), heads=64 (24 ch: q8,k8,v8),
// out 512 ch -> proj 256 ch + BN. Output y fp32.
//
// Numerics: q path (heads 0-31) fp32 via 3-term split-bf16 MFMA + fp64 fixup
// of |q|<1e-4 (degenerate-denominator relu sign flips). k/v rows single bf16
// MFMA (noise <=2e-5 at y). Row-permuted GEMM1: q rows in tiles 0-3 (split),
// k/v rows in tiles 0-7 of a second, cheaper kernel.
//
// ws (256 MiB exactly):
//   qkv_bf [0,96M)    bf16 768ch
//   qplane [96M,160M) fp32 256ch (q of heads 0-31), fixup'd in place
//   agg_bf [160M,256M) bf16 768ch; k/v slots (ch%24 in [8,24)) reused by attn
//                      for the 512-ch 'out' plane: map(o)=(o/16)*24+8+(o%16)
// d_out: kvbuf 288K scratch at head; gemm_proj (last, sole d_out writer)
// overwrites all of it.

#define NB 16
#define CQKV 768
#define P4096 4096

typedef __bf16 bf16x8 __attribute__((ext_vector_type(8)));
typedef float f32x4 __attribute__((ext_vector_type(4)));

__device__ __forceinline__ ushort f2bf(float f) {
    union { float f; unsigned int u; } x; x.f = f;
    unsigned int u = x.u;
    unsigned int r = (u + 0x7FFFu + ((u >> 16) & 1u)) >> 16;
    return (ushort)r;
}
__device__ __forceinline__ float bf2f(ushort u) {
    union { unsigned int u; float f; } x; x.u = ((unsigned int)u) << 16;
    return x.f;
}
__device__ __forceinline__ unsigned int pk2bf(float x, float y) {
    __hip_bfloat162 h = __float22bfloat162_rn(make_float2(x, y));  // v_cvt_pk_bf16_f32 (RNE)
    union { __hip_bfloat162 b; unsigned int u; } c; c.b = h; return c.u;
}
// 8 fp32 -> bf16 hi (one b128 LDS write)
__device__ __forceinline__ void stage_hi8(const float* v, ushort* dh) {
    union { unsigned int u[4]; uint4 q; } H;
    #pragma unroll
    for (int i = 0; i < 4; i++) H.u[i] = pk2bf(v[2 * i], v[2 * i + 1]);
    *(uint4*)dh = H.q;
}
// 8 fp32 -> bf16 hi + lo (two b128 LDS writes)
__device__ __forceinline__ void stage_hilo8(const float* v, ushort* dh, ushort* dl) {
    union { unsigned int u[4]; uint4 q; } H, L;
    #pragma unroll
    for (int i = 0; i < 4; i++) {
        unsigned int h = pk2bf(v[2 * i], v[2 * i + 1]);
        H.u[i] = h;
        float f0 = __uint_as_float(h << 16);
        float f1 = __uint_as_float(h & 0xffff0000u);
        L.u[i] = pk2bf(v[2 * i] - f0, v[2 * i + 1] - f1);
    }
    *(uint4*)dh = H.q;
    *(uint4*)dl = L.q;
}

// ---------------- GEMM1a: q rows (virt 0..255; phys=(v/8)*24+v%8), 3-term split ----------------
// BM=BN=64, BK=32, 256 thr = 4 waves. MFMA 16x16x32 bf16.
// A-frag: m=lane&15, k=quad*8+j ; B-frag: n=lane&15, k=quad*8+j (Bs [n][k]).
// D: col=lane&15, row=quad*4+reg.
// B staged by column loads: thread -> (n=t&63, kg=(t>>6)*8), one ds_write_b128,
// conflict-free on stride-40-ushort rows.
__global__ __launch_bounds__(256) void gemm_qkv_q(
    const float* __restrict__ A,      // 768 x 256 fp32 (phys rows)
    const float* __restrict__ X,      // b-strided 256 x 4096 fp32
    ushort* __restrict__ Cbf,         // b-strided 768 x 4096 bf16 (phys rows)
    float*  __restrict__ qplane)      // b-strided 256 x 4096 fp32 (virt q rows)
{
    const int n0 = blockIdx.x * 64;
    const int m0 = blockIdx.y * 64;   // virt q-row base
    const int b  = blockIdx.z;
    const int t  = threadIdx.x;
    const int wave = t >> 6, lane = t & 63, quad = lane >> 4, l15 = lane & 15;

    __shared__ __align__(16) ushort AsH[64][40];
    __shared__ __align__(16) ushort AsL[64][40];
    __shared__ __align__(16) ushort BsH[64][40];
    __shared__ __align__(16) ushort BsL[64][40];

    f32x4 acc[4];
    #pragma unroll
    for (int nt = 0; nt < 4; nt++)
        #pragma unroll
        for (int r = 0; r < 4; r++) acc[nt][r] = 0.0f;

    const int am = t >> 2, ak = (t & 3) * 8;
    const int arow_v = m0 + am;
    const int arow_p = (arow_v >> 3) * 24 + (arow_v & 7);
    const int bn = t & 63, kg = (t >> 6) * 8;

    for (int k0 = 0; k0 < 256; k0 += 32) {
        float av[8];
        *(float4*)&av[0] = *(const float4*)(A + (size_t)arow_p * 256 + k0 + ak);
        *(float4*)&av[4] = *(const float4*)(A + (size_t)arow_p * 256 + k0 + ak + 4);
        float bv[8];
        #pragma unroll
        for (int i = 0; i < 8; i++)
            bv[i] = X[((size_t)b * 256 + k0 + kg + i) * P4096 + n0 + bn];

        __syncthreads();
        stage_hilo8(av, &AsH[am][ak], &AsL[am][ak]);
        stage_hilo8(bv, &BsH[bn][kg], &BsL[bn][kg]);
        __syncthreads();

        bf16x8 afh = *(const bf16x8*)&AsH[wave * 16 + l15][quad * 8];
        bf16x8 afl = *(const bf16x8*)&AsL[wave * 16 + l15][quad * 8];
        #pragma unroll
        for (int nt = 0; nt < 4; nt++) {
            bf16x8 bfh = *(const bf16x8*)&BsH[nt * 16 + l15][quad * 8];
            bf16x8 bfl = *(const bf16x8*)&BsL[nt * 16 + l15][quad * 8];
            acc[nt] = __builtin_amdgcn_mfma_f32_16x16x32_bf16(afh, bfh, acc[nt], 0, 0, 0);
            acc[nt] = __builtin_amdgcn_mfma_f32_16x16x32_bf16(afl, bfh, acc[nt], 0, 0, 0);
            acc[nt] = __builtin_amdgcn_mfma_f32_16x16x32_bf16(afh, bfl, acc[nt], 0, 0, 0);
        }
    }

    #pragma unroll
    for (int nt = 0; nt < 4; nt++) {
        #pragma unroll
        for (int r = 0; r < 4; r++) {
            int rv = m0 + wave * 16 + quad * 4 + r;
            int rp = (rv >> 3) * 24 + (rv & 7);
            int col = n0 + nt * 16 + l15;
            float v = acc[nt][r];
            Cbf[((size_t)b * CQKV + rp) * P4096 + col] = f2bf(v);
            qplane[((size_t)b * 256 + rv) * P4096 + col] = v;
        }
    }
}

// ---------------- GEMM1b: k/v rows (virt2 0..511; phys=(v/16)*24+8+v%16), single MFMA ----------------
__global__ __launch_bounds__(256) void gemm_qkv_kv(
    const float* __restrict__ A, const float* __restrict__ X,
    ushort* __restrict__ Cbf)
{
    const int n0 = blockIdx.x * 64;
    const int m0 = blockIdx.y * 64;   // virt2 base
    const int b  = blockIdx.z;
    const int t  = threadIdx.x;
    const int wave = t >> 6, lane = t & 63, quad = lane >> 4, l15 = lane & 15;

    __shared__ __align__(16) ushort As[64][40];
    __shared__ __align__(16) ushort Bs[64][40];

    f32x4 acc[4];
    #pragma unroll
    for (int nt = 0; nt < 4; nt++)
        #pragma unroll
        for (int r = 0; r < 4; r++) acc[nt][r] = 0.0f;

    const int am = t >> 2, ak = (t & 3) * 8;
    const int arow_v = m0 + am;
    const int arow_p = (arow_v >> 4) * 24 + 8 + (arow_v & 15);
    const int bn = t & 63, kg = (t >> 6) * 8;

    for (int k0 = 0; k0 < 256; k0 += 32) {
        float av[8];
        *(float4*)&av[0] = *(const float4*)(A + (size_t)arow_p * 256 + k0 + ak);
        *(float4*)&av[4] = *(const float4*)(A + (size_t)arow_p * 256 + k0 + ak + 4);
        float bv[8];
        #pragma unroll
        for (int i = 0; i < 8; i++)
            bv[i] = X[((size_t)b * 256 + k0 + kg + i) * P4096 + n0 + bn];

        __syncthreads();
        stage_hi8(av, &As[am][ak]);
        stage_hi8(bv, &Bs[bn][kg]);
        __syncthreads();

        bf16x8 af = *(const bf16x8*)&As[wave * 16 + l15][quad * 8];
        #pragma unroll
        for (int nt = 0; nt < 4; nt++) {
            bf16x8 bf = *(const bf16x8*)&Bs[nt * 16 + l15][quad * 8];
            acc[nt] = __builtin_amdgcn_mfma_f32_16x16x32_bf16(af, bf, acc[nt], 0, 0, 0);
        }
    }

    #pragma unroll
    for (int nt = 0; nt < 4; nt++) {
        #pragma unroll
        for (int r = 0; r < 4; r++) {
            int rv = m0 + wave * 16 + quad * 4 + r;
            int rp = (rv >> 4) * 24 + 8 + (rv & 15);
            int col = n0 + nt * 16 + l15;
            Cbf[((size_t)b * CQKV + rp) * P4096 + col] = f2bf(acc[nt][r]);
        }
    }
}

// ---------------- qfix: recompute |q|<1e-4 in fp64 (kills relu sign flips) ----------------
__global__ __launch_bounds__(256) void qfix_kernel(
    float* __restrict__ qplane, const float* __restrict__ w_qkv,
    const float* __restrict__ x)
{
    size_t i = (size_t)blockIdx.x * 256 + threadIdx.x;  // over 16*256*4096
    float q = qplane[i];
    if (fabsf(q) >= 1e-4f) return;
    int p   = (int)(i & 4095);
    int qch = (int)((i >> 12) & 255);
    int b   = (int)(i >> 20);
    int row = (qch >> 3) * 24 + (qch & 7);
    const float* wr = w_qkv + (size_t)row * 256;
    const float* xr = x + (size_t)b * 256 * P4096 + p;
    double s = 0.0;
    for (int c = 0; c < 256; c++)
        s += (double)wr[c] * (double)xr[(size_t)c * P4096];
    qplane[i] = (float)s;
}

// ---------------- dw 3x3 + grouped pw (bf16; feeds only heads 32-63) ----------------
// v2: 512 thr, 16-row tiles, bf16 LDS (23 KB, 8-wave blocks -> 32 waves/CU),
// 2 adjacent px/thread sharing the 4-value tap window (3 conflict-free
// ds_read_b32 per (ch,dy)), weights via uniform scalar (SGPR) loads, packed
// uint stores. FMA association order identical to v1 (bitwise-same output).
__global__ __launch_bounds__(512, 8) void dwpw_kernel(
    const ushort* __restrict__ qkv, const float* __restrict__ wdw,
    const float* __restrict__ wpw, ushort* __restrict__ agg)
{
    const int rt = blockIdx.x;    // 0..3 (16 output rows each)
    const int g  = blockIdx.y;    // 0..95
    const int b  = blockIdx.z;
    const int t  = threadIdx.x;   // 0..511
    const int r0 = rt * 16;
    const int cg = g * 8;

    // bf16 tile: 8 ch x 18 rows x 80 cols. Data cols at ushort idx 8..71;
    // idx 0..7 left halo/pad (col -1 = idx 7), idx 72..79 right (col 64 = idx 72).
    // Row stride 80 ushorts = 160 B: read banks (kc + 8*row) mod 32 -> 2 lanes/bank.
    __shared__ __align__(16) ushort tile[8][18][80];   // 23040 B

    const ushort* src = qkv + ((size_t)(b * CQKV + cg)) * P4096;

    // zero halo octs (left idx 0..7, right idx 72..79), 8ch x 18rows x 2 sides
    if (t < 288) {
        int ch = t / 36;
        int rr = (t % 36) >> 1;
        int side = t & 1;
        *(uint4*)&tile[ch][rr][side * 72] = make_uint4(0, 0, 0, 0);
    }
    // stage 8ch x 18rows x 64cols bf16 = 1152 16B chunks, coalesced
    #pragma unroll
    for (int i = 0; i < 3; i++) {
        int id = t + i * 512;
        if (id < 1152) {
            int ch  = id / 144;
            int rem = id - ch * 144;
            int rr  = rem >> 3;
            int oct = (rem & 7) * 8;
            int grow = r0 - 1 + rr;
            uint4 v = make_uint4(0, 0, 0, 0);
            if (grow >= 0 && grow < 64)
                v = *(const uint4*)(src + (size_t)ch * P4096 + (size_t)grow * 64 + oct);
            *(uint4*)&tile[ch][rr][8 + oct] = v;
        }
    }
    __syncthreads();

    const int kc  = t & 31;        // col pair: cols 2kc, 2kc+1
    const int row = t >> 5;        // 0..15
    const float* wdwg = wdw + (size_t)cg * 9;   // block-uniform -> s_load
    const float* wpwg = wpw + (size_t)cg * 8;

    float acc0[8], acc1[8];
    #pragma unroll
    for (int oi = 0; oi < 8; oi++) { acc0[oi] = 0.0f; acc1[oi] = 0.0f; }

    #pragma unroll
    for (int c = 0; c < 8; c++) {
        float dv0 = 0.0f, dv1 = 0.0f;
        #pragma unroll
        for (int dy = 0; dy < 3; dy++) {
            // window cols 2kc-1 .. 2kc+2 live at ushort idx 2kc+7 .. 2kc+10
            const ushort* rp = &tile[c][row + dy][2 * kc + 4];
            unsigned int u1 = *(const unsigned int*)(rp + 2);  // cols 2kc-2, 2kc-1
            unsigned int u2 = *(const unsigned int*)(rp + 4);  // cols 2kc,   2kc+1
            unsigned int u3 = *(const unsigned int*)(rp + 6);  // cols 2kc+2, 2kc+3
            float xm1 = __uint_as_float(u1 & 0xffff0000u);
            float x0  = __uint_as_float(u2 << 16);
            float x1  = __uint_as_float(u2 & 0xffff0000u);
            float x2  = __uint_as_float(u3 << 16);
            float w0 = wdwg[c * 9 + dy * 3 + 0];
            float w1 = wdwg[c * 9 + dy * 3 + 1];
            float w2 = wdwg[c * 9 + dy * 3 + 2];
            dv0 = fmaf(w0, xm1, dv0); dv0 = fmaf(w1, x0, dv0); dv0 = fmaf(w2, x1, dv0);
            dv1 = fmaf(w0, x0,  dv1); dv1 = fmaf(w1, x1, dv1); dv1 = fmaf(w2, x2, dv1);
        }
        #pragma unroll
        for (int oi = 0; oi < 8; oi++) {
            float w = wpwg[oi * 8 + c];
            acc0[oi] = fmaf(w, dv0, acc0[oi]);
            acc1[oi] = fmaf(w, dv1, acc1[oi]);
        }
    }

    size_t obase = ((size_t)(b * CQKV + cg)) * P4096 + (size_t)(r0 + row) * 64 + 2 * kc;
    #pragma unroll
    for (int oi = 0; oi < 8; oi++) {
        unsigned int u = (unsigned int)f2bf(acc0[oi]) |
                         ((unsigned int)f2bf(acc1[oi]) << 16);
        *(unsigned int*)&agg[obase + (size_t)oi * P4096] = u;
    }
}

// ---------------- kv[b,h,d,e] = sum_p relu(k_d)*v_e  (v_8 = 1) ----------------
__global__ __launch_bounds__(256) void kv_kernel(
    const ushort* __restrict__ qkv, const ushort* __restrict__ agg,
    float* __restrict__ kv)
{
    const int h = blockIdx.x, b = blockIdx.y, t = threadIdx.x;
    const ushort* src = (h < 32)
        ? qkv + ((size_t)(b * CQKV + h * 24)) * P4096
        : agg + ((size_t)(b * CQKV + (h - 32) * 24)) * P4096;

    float acc[72];
    #pragma unroll
    for (int i = 0; i < 72; i++) acc[i] = 0.0f;

    for (int pi = 0; pi < 16; pi++) {
        int p = t + pi * 256;
        float kvv[8], vv[8];
        #pragma unroll
        for (int d = 0; d < 8; d++) {
            float xk = bf2f(src[(size_t)(8 + d) * P4096 + p]);
            kvv[d] = xk > 0.0f ? xk : 0.0f;
        }
        #pragma unroll
        for (int e = 0; e < 8; e++) vv[e] = bf2f(src[(size_t)(16 + e) * P4096 + p]);
        #pragma unroll
        for (int d = 0; d < 8; d++) {
            #pragma unroll
            for (int e = 0; e < 8; e++) acc[d * 9 + e] += kvv[d] * vv[e];
            acc[d * 9 + 8] += kvv[d];
        }
    }

    #pragma unroll
    for (int i = 0; i < 72; i++) {
        float v = acc[i];
        #pragma unroll
        for (int off = 32; off > 0; off >>= 1) v += __shfl_xor(v, off, 64);
        acc[i] = v;
    }
    __shared__ float part[4][72];
    int wave = t >> 6, lane = t & 63;
    if (lane == 0) {
        #pragma unroll
        for (int i = 0; i < 72; i++) part[wave][i] = acc[i];
    }
    __syncthreads();
    if (t < 72)
        kv[((size_t)b * 64 + h) * 72 + t] = part[0][t] + part[1][t] + part[2][t] + part[3][t];
}

// ---------------- attn: out = (q.kv)_e / ((q.kv)_8 + 1e-15) ----------------
// h<32: q from fp32 qplane (sign-exact after qfix). h>=32: q from agg bf16.
// out (bf16) written into agg's dead k/v slots: map(o)=(o/16)*24+8+(o%16).
__global__ __launch_bounds__(256) void attn_out_kernel(
    const float* __restrict__ qplane, ushort* __restrict__ agg,
    const float* __restrict__ kv)
{
    const int pt = blockIdx.x, h = blockIdx.y, b = blockIdx.z, t = threadIdx.x;
    __shared__ float kvs[72];
    if (t < 72) kvs[t] = kv[((size_t)b * 64 + h) * 72 + t];
    __syncthreads();

    const bool lohead = (h < 32);
    const float* srcf = lohead
        ? qplane + ((size_t)(b * 256 + h * 8)) * P4096 : nullptr;
    const ushort* srcb = lohead ? nullptr
        : agg + ((size_t)(b * CQKV + (h - 32) * 24)) * P4096;

    int p = pt * 256 + t;
    float num[8]; float den = 0.0f;
    #pragma unroll
    for (int e = 0; e < 8; e++) num[e] = 0.0f;
    #pragma unroll
    for (int d = 0; d < 8; d++) {
        float q = lohead ? srcf[(size_t)d * P4096 + p]
                         : bf2f(srcb[(size_t)d * P4096 + p]);
        q = q > 0.0f ? q : 0.0f;
        #pragma unroll
        for (int e = 0; e < 8; e++) num[e] += q * kvs[d * 9 + e];
        den += q * kvs[d * 9 + 8];
    }
    float rd = 1.0f / (den + 1e-15f);
    ushort* dst = agg + ((size_t)(b * CQKV + (h / 2) * 24 + 8 + (h % 2) * 8)) * P4096 + p;
    #pragma unroll
    for (int e = 0; e < 8; e++)
        dst[(size_t)e * P4096] = f2bf(num[e] * rd);
}

// ---------------- GEMM3: y = W_proj(256x512) @ out[b](512x4096), bf16, BN ----------------
__global__ __launch_bounds__(256) void gemm_proj(
    const float* __restrict__ A,       // 256 x 512 fp32
    const ushort* __restrict__ Bagg,   // out in agg's k/v slots, map(k)=(k/16)*24+8+(k%16)
    float* __restrict__ Y,
    const float* __restrict__ bn_g, const float* __restrict__ bn_b,
    const float* __restrict__ bn_m, const float* __restrict__ bn_v)
{
    const int n0 = blockIdx.x * 64;
    const int m0 = blockIdx.y * 64;
    const int b  = blockIdx.z;
    const int t  = threadIdx.x;
    const int wave = t >> 6, lane = t & 63, quad = lane >> 4, l15 = lane & 15;

    __shared__ __align__(16) ushort As[64][40];
    __shared__ __align__(16) ushort Bs[64][40];

    f32x4 acc[4];
    #pragma unroll
    for (int nt = 0; nt < 4; nt++)
        #pragma unroll
        for (int r = 0; r < 4; r++) acc[nt][r] = 0.0f;

    const int am = t >> 2, ak = (t & 3) * 8;
    const int bn = t & 63, kg = (t >> 6) * 8;

    for (int k0 = 0; k0 < 512; k0 += 32) {
        float av[8];
        *(float4*)&av[0] = *(const float4*)(A + (size_t)(m0 + am) * 512 + k0 + ak);
        *(float4*)&av[4] = *(const float4*)(A + (size_t)(m0 + am) * 512 + k0 + ak + 4);
        ushort bu[8];
        #pragma unroll
        for (int i = 0; i < 8; i++) {
            int kk = k0 + kg + i;
            int amch = (kk >> 4) * 24 + 8 + (kk & 15);
            bu[i] = Bagg[((size_t)b * CQKV + amch) * P4096 + n0 + bn];
        }

        __syncthreads();
        stage_hi8(av, &As[am][ak]);
        {
            union { ushort us[8]; uint4 q; } Bp;
            #pragma unroll
            for (int i = 0; i < 8; i++) Bp.us[i] = bu[i];
            *(uint4*)&Bs[bn][kg] = Bp.q;
        }
        __syncthreads();

        bf16x8 af = *(const bf16x8*)&As[wave * 16 + l15][quad * 8];
        #pragma unroll
        for (int nt = 0; nt < 4; nt++) {
            bf16x8 bf = *(const bf16x8*)&Bs[nt * 16 + l15][quad * 8];
            acc[nt] = __builtin_amdgcn_mfma_f32_16x16x32_bf16(af, bf, acc[nt], 0, 0, 0);
        }
    }

    #pragma unroll
    for (int nt = 0; nt < 4; nt++) {
        #pragma unroll
        for (int r = 0; r < 4; r++) {
            int row = m0 + wave * 16 + quad * 4 + r;
            int col = n0 + nt * 16 + l15;
            float inv = bn_g[row] / sqrtf(bn_v[row] + 1e-5f);
            float v = acc[nt][r] * inv + (bn_b[row] - bn_m[row] * inv);
            Y[((size_t)b * 256 + row) * P4096 + col] = v;
        }
    }
}

// ---------------- launch ----------------
extern "C" void kernel_launch(void* const* d_in, const int* in_sizes, int n_in,
                              void* d_out, int out_size, void* d_ws, size_t ws_size,
                              hipStream_t stream) {
    const float* x      = (const float*)d_in[0];
    const float* w_qkv  = (const float*)d_in[1];
    const float* w_dw   = (const float*)d_in[2];
    const float* w_pw   = (const float*)d_in[3];
    const float* w_proj = (const float*)d_in[4];
    const float* bn_g   = (const float*)d_in[5];
    const float* bn_b   = (const float*)d_in[6];
    const float* bn_m   = (const float*)d_in[7];
    const float* bn_v   = (const float*)d_in[8];
    float* y = (float*)d_out;

    char* ws = (char*)d_ws;
    ushort* qkv_bf = (ushort*)(ws);                  // 96 MiB: bf16 768ch
    float*  qplane = (float*) (ws + 100663296);      // 64 MiB: fp32 q (heads 0-31)
    ushort* agg_bf = (ushort*)(ws + 167772160);      // 96 MiB: agg; k/v slots reused for out
    float*  kvbuf  = (float*)d_out;                  // 288 KB scratch; gemm_proj overwrites

    gemm_qkv_q<<<dim3(64, 4, NB), 256, 0, stream>>>(w_qkv, x, qkv_bf, qplane);
    gemm_qkv_kv<<<dim3(64, 8, NB), 256, 0, stream>>>(w_qkv, x, qkv_bf);

    qfix_kernel<<<65536, 256, 0, stream>>>(qplane, w_qkv, x);

    dwpw_kernel<<<dim3(4, 96, NB), 512, 0, stream>>>(qkv_bf, w_dw, w_pw, agg_bf);

    kv_kernel<<<dim3(64, NB), 256, 0, stream>>>(qkv_bf, agg_bf, kvbuf);

    attn_out_kernel<<<dim3(16, 64, NB), 256, 0, stream>>>(qplane, agg_bf, kvbuf);

    gemm_proj<<<dim3(64, 4, NB), 256, 0, stream>>>(
        w_proj, agg_bf, y, bn_g, bn_b, bn_m, bn_v);
}

// Round 2
// 451.328 us; speedup vs baseline: 1.1151x; 1.0128x over previous
//
#include <hip/hip_runtime.h>
#include <hip/hip_bf16.h>

// LiteMSA pipeline, MI355X gfx950.
// B=16, Cin=256, Cqkv=768, H=W=64 (P=4096), heads=64 (24 ch: q8,k8,v8),
// out 512 ch -> proj 256 ch + BN. Output y fp32.
//
// GEMM1 (v3): pre-convert w_qkv and x to bf16 hi/lo ONCE (conv_w, conv_x),
// stored in virt-row order / transposed [p][c], pre-swizzled (16B slot ^=
// (row>>1)&3 per 64B window) so gemm_fused stages via global_load_lds w=16
// into linear LDS and reads frags with ~2-way (free) bank pattern.
// gemm_fused: 128x128 tile, 4 waves 2x2, acc 4x4; m-tiles 0-1 = q rows
// (3-term split bf16: hh+lh+hl, bitwise same order as v2), 2-5 = k/v rows
// (1-term). fp64 qfix for |q|<1e-4 unchanged.
//
// ws (256 MiB):
//   qkv_bf [0,96M)    bf16 768ch
//   qplane [96M,160M) fp32 256ch (q of heads 0-31)
//   agg_bf [160M,256M) bf16 768ch; ALIASED before dwpw by:
//     XTh [+0,32M) XTl [+32M,64M)  x^T bf16 hi/lo [b][4096][256] swizzled
//     Awh/Awl [+64M, +64.75M)      w_qkv bf16 hi/lo [768 virt][256] swizzled
//   (dwpw overwrites all of agg afterwards; attn reuses k/v slots)
// d_out: kvbuf 288K scratch at head; gemm_proj overwrites.

#define NB 16
#define CQKV 768
#define P4096 4096

typedef __bf16 bf16x8 __attribute__((ext_vector_type(8)));
typedef float f32x4 __attribute__((ext_vector_type(4)));

#define MFMA_BF16 __builtin_amdgcn_mfma_f32_16x16x32_bf16

__device__ __forceinline__ ushort f2bf(float f) {
    union { float f; unsigned int u; } x; x.f = f;
    unsigned int u = x.u;
    unsigned int r = (u + 0x7FFFu + ((u >> 16) & 1u)) >> 16;
    return (ushort)r;
}
__device__ __forceinline__ float bf2f(ushort u) {
    union { unsigned int u; float f; } x; x.u = ((unsigned int)u) << 16;
    return x.f;
}
__device__ __forceinline__ unsigned int pk2bf(float x, float y) {
    __hip_bfloat162 h = __float22bfloat162_rn(make_float2(x, y));  // v_cvt_pk_bf16_f32 (RNE)
    union { __hip_bfloat162 b; unsigned int u; } c; c.b = h; return c.u;
}
// 8 fp32 -> bf16 hi (one b128 LDS write)
__device__ __forceinline__ void stage_hi8(const float* v, ushort* dh) {
    union { unsigned int u[4]; uint4 q; } H;
    #pragma unroll
    for (int i = 0; i < 4; i++) H.u[i] = pk2bf(v[2 * i], v[2 * i + 1]);
    *(uint4*)dh = H.q;
}

__device__ __forceinline__ void gload16(void* lds, const void* g) {
    __builtin_amdgcn_global_load_lds(
        (const __attribute__((address_space(1))) void*)g,
        (__attribute__((address_space(3))) void*)lds, 16, 0, 0);
}

// ---------------- conv_w: w_qkv -> virt-row-ordered, swizzled bf16 hi/lo ----------------
// virt rows: 0..255 q (phys=(v>>3)*24+v&7), 256..767 kv (phys=(v2>>4)*24+8+v2&15).
// storage: row-major [768][256], within each 32-ushort (64B) window the 8-ushort
// chunk s goes to slot s ^ ((row>>1)&3).
__global__ __launch_bounds__(128) void conv_w(
    const float* __restrict__ W, ushort* __restrict__ Ah, ushort* __restrict__ Al)
{
    const int rv = blockIdx.x;     // 0..767
    const int t  = threadIdx.x;    // 0..127 -> c pair
    int phys;
    if (rv < 256) phys = (rv >> 3) * 24 + (rv & 7);
    else { int r2 = rv - 256; phys = (r2 >> 4) * 24 + 8 + (r2 & 15); }
    int c = t * 2;
    float w0 = W[(size_t)phys * 256 + c];
    float w1 = W[(size_t)phys * 256 + c + 1];
    unsigned int h = pk2bf(w0, w1);
    float f0 = __uint_as_float(h << 16);
    float f1 = __uint_as_float(h & 0xffff0000u);
    unsigned int l = pk2bf(w0 - f0, w1 - f1);
    int sl = ((c >> 3) & 3) ^ ((rv >> 1) & 3);
    int idx = (c & ~31) + sl * 8 + (c & 7);
    *(unsigned int*)&Ah[(size_t)rv * 256 + idx] = h;
    *(unsigned int*)&Al[(size_t)rv * 256 + idx] = l;
}

// ---------------- conv_x: x [b][256][4096] f32 -> XT hi/lo [b][4096][256] bf16, swizzled ----------------
__global__ __launch_bounds__(256) void conv_x(
    const float* __restrict__ X, ushort* __restrict__ XTh, ushort* __restrict__ XTl)
{
    const int pt = blockIdx.x;        // 0..63
    const int ct = blockIdx.y;        // 0..3
    const int b  = blockIdx.z;
    const int t  = threadIdx.x;
    const int p0 = pt * 64, c0 = ct * 64;

    __shared__ float tile[64][65];

    {
        int cr = t >> 2, pc = (t & 3) * 16;
        const float* xr = X + ((size_t)b * 256 + c0 + cr) * P4096 + p0 + pc;
        float4 v0 = *(const float4*)xr;
        float4 v1 = *(const float4*)(xr + 4);
        float4 v2 = *(const float4*)(xr + 8);
        float4 v3 = *(const float4*)(xr + 12);
        float* d = &tile[cr][pc];
        d[0]=v0.x; d[1]=v0.y; d[2]=v0.z; d[3]=v0.w;
        d[4]=v1.x; d[5]=v1.y; d[6]=v1.z; d[7]=v1.w;
        d[8]=v2.x; d[9]=v2.y; d[10]=v2.z; d[11]=v2.w;
        d[12]=v3.x; d[13]=v3.y; d[14]=v3.z; d[15]=v3.w;
    }
    __syncthreads();

    #pragma unroll
    for (int pass = 0; pass < 2; pass++) {
        int tp = t >> 2;
        int cc = (t & 3) + pass * 4;      // 0..7 chunk of 8 c
        int p  = p0 + tp;
        float v[8];
        #pragma unroll
        for (int j = 0; j < 8; j++) v[j] = tile[cc * 8 + j][tp];
        union { unsigned int u[4]; uint4 q; } H, L;
        #pragma unroll
        for (int i = 0; i < 4; i++) {
            unsigned int h = pk2bf(v[2 * i], v[2 * i + 1]);
            H.u[i] = h;
            float f0 = __uint_as_float(h << 16);
            float f1 = __uint_as_float(h & 0xffff0000u);
            L.u[i] = pk2bf(v[2 * i] - f0, v[2 * i + 1] - f1);
        }
        int c = c0 + cc * 8;
        int sl = ((c >> 3) & 3) ^ ((p >> 1) & 3);
        size_t idx = ((size_t)b * P4096 + p) * 256 + (c & ~31) + sl * 8;
        *(uint4*)&XTh[idx] = H.q;
        *(uint4*)&XTl[idx] = L.q;
    }
}

// ---------------- gemm_fused: all 768 virt rows; q tiles 3-term, kv tiles 1-term ----------------
// 128x128 tile, BK=32, 256 thr = 4 waves (2x2). Stage via global_load_lds w=16.
// LDS [128][32] ushort linear; frag read slot = quad ^ ((row>>1)&3) (storage
// pre-swizzled to match). D: col=lane&15, row=quad*4+reg.
__global__ __launch_bounds__(256, 3) void gemm_fused(
    const ushort* __restrict__ Ah, const ushort* __restrict__ Al,
    const ushort* __restrict__ Bh, const ushort* __restrict__ Bl,
    ushort* __restrict__ Cbf, float* __restrict__ qplane)
{
    const int mt = blockIdx.x;        // 0..5
    const int n0 = blockIdx.y * 128;
    const int b  = blockIdx.z;
    const int t  = threadIdx.x;
    const int wave = t >> 6, lane = t & 63, quad = lane >> 4, l15 = lane & 15;
    const int wr = wave >> 1, wc = wave & 1;
    const int M0 = mt * 128;

    __shared__ __align__(16) ushort AsH[128 * 32];
    __shared__ __align__(16) ushort AsL[128 * 32];
    __shared__ __align__(16) ushort BsH[128 * 32];
    __shared__ __align__(16) ushort BsL[128 * 32];

    int aoff[4], boff[4];
    #pragma unroll
    for (int i = 0; i < 4; i++) {
        int ra = wr * 64 + i * 16 + l15;
        aoff[i] = ra * 64 + ((quad ^ ((ra >> 1) & 3)) << 4);
        int rb = wc * 64 + i * 16 + l15;
        boff[i] = rb * 64 + ((quad ^ ((rb >> 1) & 3)) << 4);
    }

    const int srow = t >> 2;               // 0..63
    const int schunk = (t & 3) * 8;        // ushort offset in 32-ushort window
    const size_t abase = (size_t)(M0 + srow) * 256 + schunk;
    const size_t bbase = ((size_t)b * P4096 + n0 + srow) * 256 + schunk;
    const int ldsoff = wave * 1024;        // bytes; +i*4096

    f32x4 acc[4][4];
    #pragma unroll
    for (int mi = 0; mi < 4; mi++)
        #pragma unroll
        for (int nj = 0; nj < 4; nj++)
            #pragma unroll
            for (int r = 0; r < 4; r++) acc[mi][nj][r] = 0.0f;

    if (mt < 2) {
        // ---- q rows: 3-term split ----
        for (int kw = 0; kw < 8; kw++) {
            __syncthreads();
            #pragma unroll
            for (int i = 0; i < 2; i++) {
                int lo = ldsoff + i * 4096;
                size_t so = (size_t)(i * 64) * 256 + kw * 32;
                gload16((char*)AsH + lo, Ah + abase + so);
                gload16((char*)AsL + lo, Al + abase + so);
                gload16((char*)BsH + lo, Bh + bbase + so);
                gload16((char*)BsL + lo, Bl + bbase + so);
            }
            __syncthreads();
            bf16x8 ah[4], al[4];
            #pragma unroll
            for (int mi = 0; mi < 4; mi++) {
                ah[mi] = *(const bf16x8*)((const char*)AsH + aoff[mi]);
                al[mi] = *(const bf16x8*)((const char*)AsL + aoff[mi]);
            }
            #pragma unroll
            for (int nj = 0; nj < 4; nj++) {
                bf16x8 bh = *(const bf16x8*)((const char*)BsH + boff[nj]);
                bf16x8 bl = *(const bf16x8*)((const char*)BsL + boff[nj]);
                #pragma unroll
                for (int mi = 0; mi < 4; mi++) {
                    acc[mi][nj] = MFMA_BF16(ah[mi], bh, acc[mi][nj], 0, 0, 0);
                    acc[mi][nj] = MFMA_BF16(al[mi], bh, acc[mi][nj], 0, 0, 0);
                    acc[mi][nj] = MFMA_BF16(ah[mi], bl, acc[mi][nj], 0, 0, 0);
                }
            }
        }
        #pragma unroll
        for (int mi = 0; mi < 4; mi++)
            #pragma unroll
            for (int nj = 0; nj < 4; nj++)
                #pragma unroll
                for (int r = 0; r < 4; r++) {
                    int rv = M0 + wr * 64 + mi * 16 + quad * 4 + r;
                    int rp = (rv >> 3) * 24 + (rv & 7);
                    int col = n0 + wc * 64 + nj * 16 + l15;
                    float v = acc[mi][nj][r];
                    Cbf[((size_t)b * CQKV + rp) * P4096 + col] = f2bf(v);
                    qplane[((size_t)b * 256 + rv) * P4096 + col] = v;
                }
    } else {
        // ---- k/v rows: single term ----
        for (int kw = 0; kw < 8; kw++) {
            __syncthreads();
            #pragma unroll
            for (int i = 0; i < 2; i++) {
                int lo = ldsoff + i * 4096;
                size_t so = (size_t)(i * 64) * 256 + kw * 32;
                gload16((char*)AsH + lo, Ah + abase + so);
                gload16((char*)BsH + lo, Bh + bbase + so);
            }
            __syncthreads();
            bf16x8 ah[4];
            #pragma unroll
            for (int mi = 0; mi < 4; mi++)
                ah[mi] = *(const bf16x8*)((const char*)AsH + aoff[mi]);
            #pragma unroll
            for (int nj = 0; nj < 4; nj++) {
                bf16x8 bh = *(const bf16x8*)((const char*)BsH + boff[nj]);
                #pragma unroll
                for (int mi = 0; mi < 4; mi++)
                    acc[mi][nj] = MFMA_BF16(ah[mi], bh, acc[mi][nj], 0, 0, 0);
            }
        }
        #pragma unroll
        for (int mi = 0; mi < 4; mi++)
            #pragma unroll
            for (int nj = 0; nj < 4; nj++)
                #pragma unroll
                for (int r = 0; r < 4; r++) {
                    int rv2 = (M0 - 256) + wr * 64 + mi * 16 + quad * 4 + r;
                    int rp = (rv2 >> 4) * 24 + 8 + (rv2 & 15);
                    int col = n0 + wc * 64 + nj * 16 + l15;
                    Cbf[((size_t)b * CQKV + rp) * P4096 + col] = f2bf(acc[mi][nj][r]);
                }
    }
}

// ---------------- qfix: recompute |q|<1e-4 in fp64 (kills relu sign flips) ----------------
__global__ __launch_bounds__(256) void qfix_kernel(
    float* __restrict__ qplane, const float* __restrict__ w_qkv,
    const float* __restrict__ x)
{
    size_t i = (size_t)blockIdx.x * 256 + threadIdx.x;  // over 16*256*4096
    float q = qplane[i];
    if (fabsf(q) >= 1e-4f) return;
    int p   = (int)(i & 4095);
    int qch = (int)((i >> 12) & 255);
    int b   = (int)(i >> 20);
    int row = (qch >> 3) * 24 + (qch & 7);
    const float* wr = w_qkv + (size_t)row * 256;
    const float* xr = x + (size_t)b * 256 * P4096 + p;
    double s = 0.0;
    for (int c = 0; c < 256; c++)
        s += (double)wr[c] * (double)xr[(size_t)c * P4096];
    qplane[i] = (float)s;
}

// ---------------- dw 3x3 + grouped pw (bf16; feeds only heads 32-63) ----------------
// 512 thr, 16-row tiles, bf16 LDS (23 KB, 8-wave blocks -> 32 waves/CU),
// 2 adjacent px/thread sharing the 4-value tap window, weights via uniform
// scalar (SGPR) loads, packed uint stores.
__global__ __launch_bounds__(512, 8) void dwpw_kernel(
    const ushort* __restrict__ qkv, const float* __restrict__ wdw,
    const float* __restrict__ wpw, ushort* __restrict__ agg)
{
    const int rt = blockIdx.x;    // 0..3 (16 output rows each)
    const int g  = blockIdx.y;    // 0..95
    const int b  = blockIdx.z;
    const int t  = threadIdx.x;   // 0..511
    const int r0 = rt * 16;
    const int cg = g * 8;

    __shared__ __align__(16) ushort tile[8][18][80];   // 23040 B

    const ushort* src = qkv + ((size_t)(b * CQKV + cg)) * P4096;

    if (t < 288) {
        int ch = t / 36;
        int rr = (t % 36) >> 1;
        int side = t & 1;
        *(uint4*)&tile[ch][rr][side * 72] = make_uint4(0, 0, 0, 0);
    }
    #pragma unroll
    for (int i = 0; i < 3; i++) {
        int id = t + i * 512;
        if (id < 1152) {
            int ch  = id / 144;
            int rem = id - ch * 144;
            int rr  = rem >> 3;
            int oct = (rem & 7) * 8;
            int grow = r0 - 1 + rr;
            uint4 v = make_uint4(0, 0, 0, 0);
            if (grow >= 0 && grow < 64)
                v = *(const uint4*)(src + (size_t)ch * P4096 + (size_t)grow * 64 + oct);
            *(uint4*)&tile[ch][rr][8 + oct] = v;
        }
    }
    __syncthreads();

    const int kc  = t & 31;        // col pair: cols 2kc, 2kc+1
    const int row = t >> 5;        // 0..15
    const float* wdwg = wdw + (size_t)cg * 9;   // block-uniform -> s_load
    const float* wpwg = wpw + (size_t)cg * 8;

    float acc0[8], acc1[8];
    #pragma unroll
    for (int oi = 0; oi < 8; oi++) { acc0[oi] = 0.0f; acc1[oi] = 0.0f; }

    #pragma unroll
    for (int c = 0; c < 8; c++) {
        float dv0 = 0.0f, dv1 = 0.0f;
        #pragma unroll
        for (int dy = 0; dy < 3; dy++) {
            const ushort* rp = &tile[c][row + dy][2 * kc + 4];
            unsigned int u1 = *(const unsigned int*)(rp + 2);
            unsigned int u2 = *(const unsigned int*)(rp + 4);
            unsigned int u3 = *(const unsigned int*)(rp + 6);
            float xm1 = __uint_as_float(u1 & 0xffff0000u);
            float x0  = __uint_as_float(u2 << 16);
            float x1  = __uint_as_float(u2 & 0xffff0000u);
            float x2  = __uint_as_float(u3 << 16);
            float w0 = wdwg[c * 9 + dy * 3 + 0];
            float w1 = wdwg[c * 9 + dy * 3 + 1];
            float w2 = wdwg[c * 9 + dy * 3 + 2];
            dv0 = fmaf(w0, xm1, dv0); dv0 = fmaf(w1, x0, dv0); dv0 = fmaf(w2, x1, dv0);
            dv1 = fmaf(w0, x0,  dv1); dv1 = fmaf(w1, x1, dv1); dv1 = fmaf(w2, x2, dv1);
        }
        #pragma unroll
        for (int oi = 0; oi < 8; oi++) {
            float w = wpwg[oi * 8 + c];
            acc0[oi] = fmaf(w, dv0, acc0[oi]);
            acc1[oi] = fmaf(w, dv1, acc1[oi]);
        }
    }

    size_t obase = ((size_t)(b * CQKV + cg)) * P4096 + (size_t)(r0 + row) * 64 + 2 * kc;
    #pragma unroll
    for (int oi = 0; oi < 8; oi++) {
        unsigned int u = (unsigned int)f2bf(acc0[oi]) |
                         ((unsigned int)f2bf(acc1[oi]) << 16);
        *(unsigned int*)&agg[obase + (size_t)oi * P4096] = u;
    }
}

// ---------------- kv[b,h,d,e] = sum_p relu(k_d)*v_e  (v_8 = 1) ----------------
__global__ __launch_bounds__(256) void kv_kernel(
    const ushort* __restrict__ qkv, const ushort* __restrict__ agg,
    float* __restrict__ kv)
{
    const int h = blockIdx.x, b = blockIdx.y, t = threadIdx.x;
    const ushort* src = (h < 32)
        ? qkv + ((size_t)(b * CQKV + h * 24)) * P4096
        : agg + ((size_t)(b * CQKV + (h - 32) * 24)) * P4096;

    float acc[72];
    #pragma unroll
    for (int i = 0; i < 72; i++) acc[i] = 0.0f;

    for (int pi = 0; pi < 16; pi++) {
        int p = t + pi * 256;
        float kvv[8], vv[8];
        #pragma unroll
        for (int d = 0; d < 8; d++) {
            float xk = bf2f(src[(size_t)(8 + d) * P4096 + p]);
            kvv[d] = xk > 0.0f ? xk : 0.0f;
        }
        #pragma unroll
        for (int e = 0; e < 8; e++) vv[e] = bf2f(src[(size_t)(16 + e) * P4096 + p]);
        #pragma unroll
        for (int d = 0; d < 8; d++) {
            #pragma unroll
            for (int e = 0; e < 8; e++) acc[d * 9 + e] += kvv[d] * vv[e];
            acc[d * 9 + 8] += kvv[d];
        }
    }

    #pragma unroll
    for (int i = 0; i < 72; i++) {
        float v = acc[i];
        #pragma unroll
        for (int off = 32; off > 0; off >>= 1) v += __shfl_xor(v, off, 64);
        acc[i] = v;
    }
    __shared__ float part[4][72];
    int wave = t >> 6, lane = t & 63;
    if (lane == 0) {
        #pragma unroll
        for (int i = 0; i < 72; i++) part[wave][i] = acc[i];
    }
    __syncthreads();
    if (t < 72)
        kv[((size_t)b * 64 + h) * 72 + t] = part[0][t] + part[1][t] + part[2][t] + part[3][t];
}

// ---------------- attn: out = (q.kv)_e / ((q.kv)_8 + 1e-15) ----------------
__global__ __launch_bounds__(256) void attn_out_kernel(
    const float* __restrict__ qplane, ushort* __restrict__ agg,
    const float* __restrict__ kv)
{
    const int pt = blockIdx.x, h = blockIdx.y, b = blockIdx.z, t = threadIdx.x;
    __shared__ float kvs[72];
    if (t < 72) kvs[t] = kv[((size_t)b * 64 + h) * 72 + t];
    __syncthreads();

    const bool lohead = (h < 32);
    const float* srcf = lohead
        ? qplane + ((size_t)(b * 256 + h * 8)) * P4096 : nullptr;
    const ushort* srcb = lohead ? nullptr
        : agg + ((size_t)(b * CQKV + (h - 32) * 24)) * P4096;

    int p = pt * 256 + t;
    float num[8]; float den = 0.0f;
    #pragma unroll
    for (int e = 0; e < 8; e++) num[e] = 0.0f;
    #pragma unroll
    for (int d = 0; d < 8; d++) {
        float q = lohead ? srcf[(size_t)d * P4096 + p]
                         : bf2f(srcb[(size_t)d * P4096 + p]);
        q = q > 0.0f ? q : 0.0f;
        #pragma unroll
        for (int e = 0; e < 8; e++) num[e] += q * kvs[d * 9 + e];
        den += q * kvs[d * 9 + 8];
    }
    float rd = 1.0f / (den + 1e-15f);
    ushort* dst = agg + ((size_t)(b * CQKV + (h / 2) * 24 + 8 + (h % 2) * 8)) * P4096 + p;
    #pragma unroll
    for (int e = 0; e < 8; e++)
        dst[(size_t)e * P4096] = f2bf(num[e] * rd);
}

// ---------------- GEMM3: y = W_proj(256x512) @ out[b](512x4096), bf16, BN ----------------
__global__ __launch_bounds__(256) void gemm_proj(
    const float* __restrict__ A,       // 256 x 512 fp32
    const ushort* __restrict__ Bagg,   // out in agg's k/v slots, map(k)=(k/16)*24+8+(k%16)
    float* __restrict__ Y,
    const float* __restrict__ bn_g, const float* __restrict__ bn_b,
    const float* __restrict__ bn_m, const float* __restrict__ bn_v)
{
    const int n0 = blockIdx.x * 64;
    const int m0 = blockIdx.y * 64;
    const int b  = blockIdx.z;
    const int t  = threadIdx.x;
    const int wave = t >> 6, lane = t & 63, quad = lane >> 4, l15 = lane & 15;

    __shared__ __align__(16) ushort As[64][40];
    __shared__ __align__(16) ushort Bs[64][40];

    f32x4 acc[4];
    #pragma unroll
    for (int nt = 0; nt < 4; nt++)
        #pragma unroll
        for (int r = 0; r < 4; r++) acc[nt][r] = 0.0f;

    const int am = t >> 2, ak = (t & 3) * 8;
    const int bn = t & 63, kg = (t >> 6) * 8;

    for (int k0 = 0; k0 < 512; k0 += 32) {
        float av[8];
        *(float4*)&av[0] = *(const float4*)(A + (size_t)(m0 + am) * 512 + k0 + ak);
        *(float4*)&av[4] = *(const float4*)(A + (size_t)(m0 + am) * 512 + k0 + ak + 4);
        ushort bu[8];
        #pragma unroll
        for (int i = 0; i < 8; i++) {
            int kk = k0 + kg + i;
            int amch = (kk >> 4) * 24 + 8 + (kk & 15);
            bu[i] = Bagg[((size_t)b * CQKV + amch) * P4096 + n0 + bn];
        }

        __syncthreads();
        stage_hi8(av, &As[am][ak]);
        {
            union { ushort us[8]; uint4 q; } Bp;
            #pragma unroll
            for (int i = 0; i < 8; i++) Bp.us[i] = bu[i];
            *(uint4*)&Bs[bn][kg] = Bp.q;
        }
        __syncthreads();

        bf16x8 af = *(const bf16x8*)&As[wave * 16 + l15][quad * 8];
        #pragma unroll
        for (int nt = 0; nt < 4; nt++) {
            bf16x8 bf = *(const bf16x8*)&Bs[nt * 16 + l15][quad * 8];
            acc[nt] = MFMA_BF16(af, bf, acc[nt], 0, 0, 0);
        }
    }

    #pragma unroll
    for (int nt = 0; nt < 4; nt++) {
        #pragma unroll
        for (int r = 0; r < 4; r++) {
            int row = m0 + wave * 16 + quad * 4 + r;
            int col = n0 + nt * 16 + l15;
            float inv = bn_g[row] / sqrtf(bn_v[row] + 1e-5f);
            float v = acc[nt][r] * inv + (bn_b[row] - bn_m[row] * inv);
            Y[((size_t)b * 256 + row) * P4096 + col] = v;
        }
    }
}

// ---------------- launch ----------------
extern "C" void kernel_launch(void* const* d_in, const int* in_sizes, int n_in,
                              void* d_out, int out_size, void* d_ws, size_t ws_size,
                              hipStream_t stream) {
    const float* x      = (const float*)d_in[0];
    const float* w_qkv  = (const float*)d_in[1];
    const float* w_dw   = (const float*)d_in[2];
    const float* w_pw   = (const float*)d_in[3];
    const float* w_proj = (const float*)d_in[4];
    const float* bn_g   = (const float*)d_in[5];
    const float* bn_b   = (const float*)d_in[6];
    const float* bn_m   = (const float*)d_in[7];
    const float* bn_v   = (const float*)d_in[8];
    float* y = (float*)d_out;

    char* ws = (char*)d_ws;
    ushort* qkv_bf = (ushort*)(ws);                  // 96 MiB: bf16 768ch
    float*  qplane = (float*) (ws + 100663296);      // 64 MiB: fp32 q (heads 0-31)
    ushort* agg_bf = (ushort*)(ws + 167772160);      // 96 MiB: agg; k/v slots reused for out
    // aliases inside agg region, dead once dwpw runs:
    ushort* XTh = (ushort*)(ws + 167772160);                       // 32 MiB
    ushort* XTl = (ushort*)(ws + 167772160 + 33554432);            // 32 MiB
    ushort* Awh = (ushort*)(ws + 167772160 + 67108864);            // 384 KiB
    ushort* Awl = (ushort*)(ws + 167772160 + 67108864 + 393216);   // 384 KiB
    float*  kvbuf  = (float*)d_out;                  // 288 KB scratch; gemm_proj overwrites

    conv_w<<<dim3(768), 128, 0, stream>>>(w_qkv, Awh, Awl);
    conv_x<<<dim3(64, 4, NB), 256, 0, stream>>>(x, XTh, XTl);

    gemm_fused<<<dim3(6, 32, NB), 256, 0, stream>>>(
        Awh, Awl, XTh, XTl, qkv_bf, qplane);

    qfix_kernel<<<65536, 256, 0, stream>>>(qplane, w_qkv, x);

    dwpw_kernel<<<dim3(4, 96, NB), 512, 0, stream>>>(qkv_bf, w_dw, w_pw, agg_bf);

    kv_kernel<<<dim3(64, NB), 256, 0, stream>>>(qkv_bf, agg_bf, kvbuf);

    attn_out_kernel<<<dim3(16, 64, NB), 256, 0, stream>>>(qplane, agg_bf, kvbuf);

    gemm_proj<<<dim3(64, 4, NB), 256, 0, stream>>>(
        w_proj, agg_bf, y, bn_g, bn_b, bn_m, bn_v);
}

// Round 3
// 445.828 us; speedup vs baseline: 1.1289x; 1.0123x over previous
//
#include <hip/hip_runtime.h>
#include <hip/hip_bf16.h>

// LiteMSA pipeline, MI355X gfx950.
// B=16, Cin=256, Cqkv=768, H=W=64 (P=4096), heads=64 (24 ch: q8,k8,v8),
// out 512 ch -> proj 256 ch + BN. Output y fp32.
//
// GEMM1 (v4): pre-convert w_qkv and x to bf16 hi/lo ONCE (conv_w, conv_x),
// stored in virt-row order / transposed [p][c], pre-swizzled (16B slot ^=
// (row>>1)&3 per 64B window) so gemm_fused stages via global_load_lds w=16
// into linear LDS and reads frags with ~2-way (free) bank pattern.
// gemm_fused: 128x128 tile, 4 waves 2x2, acc 4x4; m-tiles 0-1 = q rows
// (3-term split bf16: hh+lh+hl), 2-5 = k/v rows (1-term).
// v4: double-buffered LDS prefetch (stage k+1 before compute k, ONE barrier
// per K-step) + XCD-contiguous block swizzle (6 mt-blocks sharing a B-slice
// land on one XCD's L2). fp64 qfix for |q|<1e-4 unchanged.
//
// ws (256 MiB):
//   qkv_bf [0,96M)    bf16 768ch
//   qplane [96M,160M) fp32 256ch (q of heads 0-31)
//   agg_bf [160M,256M) bf16 768ch; ALIASED before dwpw by:
//     XTh [+0,32M) XTl [+32M,64M)  x^T bf16 hi/lo [b][4096][256] swizzled
//     Awh/Awl [+64M, +64.75M)      w_qkv bf16 hi/lo [768 virt][256] swizzled
//   (dwpw overwrites all of agg afterwards; attn reuses k/v slots)
// d_out: kvbuf 288K scratch at head; gemm_proj overwrites.

#define NB 16
#define CQKV 768
#define P4096 4096

typedef __bf16 bf16x8 __attribute__((ext_vector_type(8)));
typedef float f32x4 __attribute__((ext_vector_type(4)));

#define MFMA_BF16 __builtin_amdgcn_mfma_f32_16x16x32_bf16

__device__ __forceinline__ ushort f2bf(float f) {
    union { float f; unsigned int u; } x; x.f = f;
    unsigned int u = x.u;
    unsigned int r = (u + 0x7FFFu + ((u >> 16) & 1u)) >> 16;
    return (ushort)r;
}
__device__ __forceinline__ float bf2f(ushort u) {
    union { unsigned int u; float f; } x; x.u = ((unsigned int)u) << 16;
    return x.f;
}
__device__ __forceinline__ unsigned int pk2bf(float x, float y) {
    __hip_bfloat162 h = __float22bfloat162_rn(make_float2(x, y));  // v_cvt_pk_bf16_f32 (RNE)
    union { __hip_bfloat162 b; unsigned int u; } c; c.b = h; return c.u;
}
// 8 fp32 -> bf16 hi (one b128 LDS write)
__device__ __forceinline__ void stage_hi8(const float* v, ushort* dh) {
    union { unsigned int u[4]; uint4 q; } H;
    #pragma unroll
    for (int i = 0; i < 4; i++) H.u[i] = pk2bf(v[2 * i], v[2 * i + 1]);
    *(uint4*)dh = H.q;
}

__device__ __forceinline__ void gload16(void* lds, const void* g) {
    __builtin_amdgcn_global_load_lds(
        (const __attribute__((address_space(1))) void*)g,
        (__attribute__((address_space(3))) void*)lds, 16, 0, 0);
}

// ---------------- conv_w: w_qkv -> virt-row-ordered, swizzled bf16 hi/lo ----------------
// virt rows: 0..255 q (phys=(v>>3)*24+v&7), 256..767 kv (phys=(v2>>4)*24+8+v2&15).
// storage: row-major [768][256], within each 32-ushort (64B) window the 8-ushort
// chunk s goes to slot s ^ ((row>>1)&3).
__global__ __launch_bounds__(128) void conv_w(
    const float* __restrict__ W, ushort* __restrict__ Ah, ushort* __restrict__ Al)
{
    const int rv = blockIdx.x;     // 0..767
    const int t  = threadIdx.x;    // 0..127 -> c pair
    int phys;
    if (rv < 256) phys = (rv >> 3) * 24 + (rv & 7);
    else { int r2 = rv - 256; phys = (r2 >> 4) * 24 + 8 + (r2 & 15); }
    int c = t * 2;
    float w0 = W[(size_t)phys * 256 + c];
    float w1 = W[(size_t)phys * 256 + c + 1];
    unsigned int h = pk2bf(w0, w1);
    float f0 = __uint_as_float(h << 16);
    float f1 = __uint_as_float(h & 0xffff0000u);
    unsigned int l = pk2bf(w0 - f0, w1 - f1);
    int sl = ((c >> 3) & 3) ^ ((rv >> 1) & 3);
    int idx = (c & ~31) + sl * 8 + (c & 7);
    *(unsigned int*)&Ah[(size_t)rv * 256 + idx] = h;
    *(unsigned int*)&Al[(size_t)rv * 256 + idx] = l;
}

// ---------------- conv_x: x [b][256][4096] f32 -> XT hi/lo [b][4096][256] bf16, swizzled ----------------
__global__ __launch_bounds__(256) void conv_x(
    const float* __restrict__ X, ushort* __restrict__ XTh, ushort* __restrict__ XTl)
{
    const int pt = blockIdx.x;        // 0..63
    const int ct = blockIdx.y;        // 0..3
    const int b  = blockIdx.z;
    const int t  = threadIdx.x;
    const int p0 = pt * 64, c0 = ct * 64;

    __shared__ float tile[64][65];

    {
        int cr = t >> 2, pc = (t & 3) * 16;
        const float* xr = X + ((size_t)b * 256 + c0 + cr) * P4096 + p0 + pc;
        float4 v0 = *(const float4*)xr;
        float4 v1 = *(const float4*)(xr + 4);
        float4 v2 = *(const float4*)(xr + 8);
        float4 v3 = *(const float4*)(xr + 12);
        float* d = &tile[cr][pc];
        d[0]=v0.x; d[1]=v0.y; d[2]=v0.z; d[3]=v0.w;
        d[4]=v1.x; d[5]=v1.y; d[6]=v1.z; d[7]=v1.w;
        d[8]=v2.x; d[9]=v2.y; d[10]=v2.z; d[11]=v2.w;
        d[12]=v3.x; d[13]=v3.y; d[14]=v3.z; d[15]=v3.w;
    }
    __syncthreads();

    #pragma unroll
    for (int pass = 0; pass < 2; pass++) {
        int tp = t >> 2;
        int cc = (t & 3) + pass * 4;      // 0..7 chunk of 8 c
        int p  = p0 + tp;
        float v[8];
        #pragma unroll
        for (int j = 0; j < 8; j++) v[j] = tile[cc * 8 + j][tp];
        union { unsigned int u[4]; uint4 q; } H, L;
        #pragma unroll
        for (int i = 0; i < 4; i++) {
            unsigned int h = pk2bf(v[2 * i], v[2 * i + 1]);
            H.u[i] = h;
            float f0 = __uint_as_float(h << 16);
            float f1 = __uint_as_float(h & 0xffff0000u);
            L.u[i] = pk2bf(v[2 * i] - f0, v[2 * i + 1] - f1);
        }
        int c = c0 + cc * 8;
        int sl = ((c >> 3) & 3) ^ ((p >> 1) & 3);
        size_t idx = ((size_t)b * P4096 + p) * 256 + (c & ~31) + sl * 8;
        *(uint4*)&XTh[idx] = H.q;
        *(uint4*)&XTl[idx] = L.q;
    }
}

// ---------------- gemm_fused: all 768 virt rows; q tiles 3-term, kv tiles 1-term ----------------
// 128x128 tile, BK=32, 256 thr = 4 waves (2x2). Stage via global_load_lds w=16,
// double-buffered: stage window kw+1 into buf^1 BEFORE computing buf (one
// __syncthreads per K-step; its vmcnt(0)+lgkmcnt(0) drain is the pipeline sync).
// LDS [128][32] ushort linear per buf; frag read slot = quad ^ ((row>>1)&3)
// (storage pre-swizzled to match). D: col=lane&15, row=quad*4+reg.
// Grid: 1-D 3072, XCD-contiguous swizzle lg=(hw&7)*384+(hw>>3) so the 6
// mt-blocks sharing a B-slice run on one XCD (B hits its L2).
__global__ __launch_bounds__(256, 2) void gemm_fused(
    const ushort* __restrict__ Ah, const ushort* __restrict__ Al,
    const ushort* __restrict__ Bh, const ushort* __restrict__ Bl,
    ushort* __restrict__ Cbf, float* __restrict__ qplane)
{
    const int hw = blockIdx.x;                 // 0..3071
    const int lg = (hw & 7) * 384 + (hw >> 3); // XCD-contiguous logical id
    const int mt = lg % 6;
    const int rem = lg / 6;                    // 0..511
    const int n0 = (rem & 31) * 128;
    const int b  = rem >> 5;
    const int t  = threadIdx.x;
    const int wave = t >> 6, lane = t & 63, quad = lane >> 4, l15 = lane & 15;
    const int wr = wave >> 1, wc = wave & 1;
    const int M0 = mt * 128;

    __shared__ __align__(16) ushort AsH[2][4096];
    __shared__ __align__(16) ushort AsL[2][4096];
    __shared__ __align__(16) ushort BsH[2][4096];
    __shared__ __align__(16) ushort BsL[2][4096];

    int aoff[4], boff[4];
    #pragma unroll
    for (int i = 0; i < 4; i++) {
        int ra = wr * 64 + i * 16 + l15;
        aoff[i] = ra * 64 + ((quad ^ ((ra >> 1) & 3)) << 4);
        int rb = wc * 64 + i * 16 + l15;
        boff[i] = rb * 64 + ((quad ^ ((rb >> 1) & 3)) << 4);
    }

    const int srow = t >> 2;               // 0..63
    const int schunk = (t & 3) * 8;        // ushort offset in 32-ushort window
    const size_t abase = (size_t)(M0 + srow) * 256 + schunk;
    const size_t bbase = ((size_t)b * P4096 + n0 + srow) * 256 + schunk;
    const int ldsoff = wave * 1024;        // bytes; +i*4096

    f32x4 acc[4][4];
    #pragma unroll
    for (int mi = 0; mi < 4; mi++)
        #pragma unroll
        for (int nj = 0; nj < 4; nj++)
            #pragma unroll
            for (int r = 0; r < 4; r++) acc[mi][nj][r] = 0.0f;

    if (mt < 2) {
        // ---- q rows: 3-term split ----
        auto stageQ = [&](int d, int kw) {
            #pragma unroll
            for (int i = 0; i < 2; i++) {
                int lo = ldsoff + i * 4096;
                size_t so = (size_t)(i * 64) * 256 + (size_t)kw * 32;
                gload16((char*)AsH[d] + lo, Ah + abase + so);
                gload16((char*)AsL[d] + lo, Al + abase + so);
                gload16((char*)BsH[d] + lo, Bh + bbase + so);
                gload16((char*)BsL[d] + lo, Bl + bbase + so);
            }
        };
        stageQ(0, 0);
        __syncthreads();
        for (int kw = 0; kw < 8; kw++) {
            int cur = kw & 1;
            if (kw < 7) stageQ(cur ^ 1, kw + 1);
            bf16x8 ah[4], al[4];
            #pragma unroll
            for (int mi = 0; mi < 4; mi++) {
                ah[mi] = *(const bf16x8*)((const char*)AsH[cur] + aoff[mi]);
                al[mi] = *(const bf16x8*)((const char*)AsL[cur] + aoff[mi]);
            }
            #pragma unroll
            for (int nj = 0; nj < 4; nj++) {
                bf16x8 bh = *(const bf16x8*)((const char*)BsH[cur] + boff[nj]);
                bf16x8 bl = *(const bf16x8*)((const char*)BsL[cur] + boff[nj]);
                #pragma unroll
                for (int mi = 0; mi < 4; mi++) {
                    acc[mi][nj] = MFMA_BF16(ah[mi], bh, acc[mi][nj], 0, 0, 0);
                    acc[mi][nj] = MFMA_BF16(al[mi], bh, acc[mi][nj], 0, 0, 0);
                    acc[mi][nj] = MFMA_BF16(ah[mi], bl, acc[mi][nj], 0, 0, 0);
                }
            }
            __syncthreads();
        }
        #pragma unroll
        for (int mi = 0; mi < 4; mi++)
            #pragma unroll
            for (int nj = 0; nj < 4; nj++)
                #pragma unroll
                for (int r = 0; r < 4; r++) {
                    int rv = M0 + wr * 64 + mi * 16 + quad * 4 + r;
                    int rp = (rv >> 3) * 24 + (rv & 7);
                    int col = n0 + wc * 64 + nj * 16 + l15;
                    float v = acc[mi][nj][r];
                    Cbf[((size_t)b * CQKV + rp) * P4096 + col] = f2bf(v);
                    qplane[((size_t)b * 256 + rv) * P4096 + col] = v;
                }
    } else {
        // ---- k/v rows: single term ----
        auto stageKV = [&](int d, int kw) {
            #pragma unroll
            for (int i = 0; i < 2; i++) {
                int lo = ldsoff + i * 4096;
                size_t so = (size_t)(i * 64) * 256 + (size_t)kw * 32;
                gload16((char*)AsH[d] + lo, Ah + abase + so);
                gload16((char*)BsH[d] + lo, Bh + bbase + so);
            }
        };
        stageKV(0, 0);
        __syncthreads();
        for (int kw = 0; kw < 8; kw++) {
            int cur = kw & 1;
            if (kw < 7) stageKV(cur ^ 1, kw + 1);
            bf16x8 ah[4];
            #pragma unroll
            for (int mi = 0; mi < 4; mi++)
                ah[mi] = *(const bf16x8*)((const char*)AsH[cur] + aoff[mi]);
            #pragma unroll
            for (int nj = 0; nj < 4; nj++) {
                bf16x8 bh = *(const bf16x8*)((const char*)BsH[cur] + boff[nj]);
                #pragma unroll
                for (int mi = 0; mi < 4; mi++)
                    acc[mi][nj] = MFMA_BF16(ah[mi], bh, acc[mi][nj], 0, 0, 0);
            }
            __syncthreads();
        }
        #pragma unroll
        for (int mi = 0; mi < 4; mi++)
            #pragma unroll
            for (int nj = 0; nj < 4; nj++)
                #pragma unroll
                for (int r = 0; r < 4; r++) {
                    int rv2 = (M0 - 256) + wr * 64 + mi * 16 + quad * 4 + r;
                    int rp = (rv2 >> 4) * 24 + 8 + (rv2 & 15);
                    int col = n0 + wc * 64 + nj * 16 + l15;
                    Cbf[((size_t)b * CQKV + rp) * P4096 + col] = f2bf(acc[mi][nj][r]);
                }
    }
}

// ---------------- qfix: recompute |q|<1e-4 in fp64 (kills relu sign flips) ----------------
__global__ __launch_bounds__(256) void qfix_kernel(
    float* __restrict__ qplane, const float* __restrict__ w_qkv,
    const float* __restrict__ x)
{
    size_t i = (size_t)blockIdx.x * 256 + threadIdx.x;  // over 16*256*4096
    float q = qplane[i];
    if (fabsf(q) >= 1e-4f) return;
    int p   = (int)(i & 4095);
    int qch = (int)((i >> 12) & 255);
    int b   = (int)(i >> 20);
    int row = (qch >> 3) * 24 + (qch & 7);
    const float* wr = w_qkv + (size_t)row * 256;
    const float* xr = x + (size_t)b * 256 * P4096 + p;
    double s = 0.0;
    for (int c = 0; c < 256; c++)
        s += (double)wr[c] * (double)xr[(size_t)c * P4096];
    qplane[i] = (float)s;
}

// ---------------- dw 3x3 + grouped pw (bf16; feeds only heads 32-63) ----------------
// 512 thr, 16-row tiles, bf16 LDS (23 KB, 8-wave blocks -> 32 waves/CU),
// 2 adjacent px/thread sharing the 4-value tap window, weights via uniform
// scalar (SGPR) loads, packed uint stores.
__global__ __launch_bounds__(512, 8) void dwpw_kernel(
    const ushort* __restrict__ qkv, const float* __restrict__ wdw,
    const float* __restrict__ wpw, ushort* __restrict__ agg)
{
    const int rt = blockIdx.x;    // 0..3 (16 output rows each)
    const int g  = blockIdx.y;    // 0..95
    const int b  = blockIdx.z;
    const int t  = threadIdx.x;   // 0..511
    const int r0 = rt * 16;
    const int cg = g * 8;

    __shared__ __align__(16) ushort tile[8][18][80];   // 23040 B

    const ushort* src = qkv + ((size_t)(b * CQKV + cg)) * P4096;

    if (t < 288) {
        int ch = t / 36;
        int rr = (t % 36) >> 1;
        int side = t & 1;
        *(uint4*)&tile[ch][rr][side * 72] = make_uint4(0, 0, 0, 0);
    }
    #pragma unroll
    for (int i = 0; i < 3; i++) {
        int id = t + i * 512;
        if (id < 1152) {
            int ch  = id / 144;
            int rem = id - ch * 144;
            int rr  = rem >> 3;
            int oct = (rem & 7) * 8;
            int grow = r0 - 1 + rr;
            uint4 v = make_uint4(0, 0, 0, 0);
            if (grow >= 0 && grow < 64)
                v = *(const uint4*)(src + (size_t)ch * P4096 + (size_t)grow * 64 + oct);
            *(uint4*)&tile[ch][rr][8 + oct] = v;
        }
    }
    __syncthreads();

    const int kc  = t & 31;        // col pair: cols 2kc, 2kc+1
    const int row = t >> 5;        // 0..15
    const float* wdwg = wdw + (size_t)cg * 9;   // block-uniform -> s_load
    const float* wpwg = wpw + (size_t)cg * 8;

    float acc0[8], acc1[8];
    #pragma unroll
    for (int oi = 0; oi < 8; oi++) { acc0[oi] = 0.0f; acc1[oi] = 0.0f; }

    #pragma unroll
    for (int c = 0; c < 8; c++) {
        float dv0 = 0.0f, dv1 = 0.0f;
        #pragma unroll
        for (int dy = 0; dy < 3; dy++) {
            const ushort* rp = &tile[c][row + dy][2 * kc + 4];
            unsigned int u1 = *(const unsigned int*)(rp + 2);
            unsigned int u2 = *(const unsigned int*)(rp + 4);
            unsigned int u3 = *(const unsigned int*)(rp + 6);
            float xm1 = __uint_as_float(u1 & 0xffff0000u);
            float x0  = __uint_as_float(u2 << 16);
            float x1  = __uint_as_float(u2 & 0xffff0000u);
            float x2  = __uint_as_float(u3 << 16);
            float w0 = wdwg[c * 9 + dy * 3 + 0];
            float w1 = wdwg[c * 9 + dy * 3 + 1];
            float w2 = wdwg[c * 9 + dy * 3 + 2];
            dv0 = fmaf(w0, xm1, dv0); dv0 = fmaf(w1, x0, dv0); dv0 = fmaf(w2, x1, dv0);
            dv1 = fmaf(w0, x0,  dv1); dv1 = fmaf(w1, x1, dv1); dv1 = fmaf(w2, x2, dv1);
        }
        #pragma unroll
        for (int oi = 0; oi < 8; oi++) {
            float w = wpwg[oi * 8 + c];
            acc0[oi] = fmaf(w, dv0, acc0[oi]);
            acc1[oi] = fmaf(w, dv1, acc1[oi]);
        }
    }

    size_t obase = ((size_t)(b * CQKV + cg)) * P4096 + (size_t)(r0 + row) * 64 + 2 * kc;
    #pragma unroll
    for (int oi = 0; oi < 8; oi++) {
        unsigned int u = (unsigned int)f2bf(acc0[oi]) |
                         ((unsigned int)f2bf(acc1[oi]) << 16);
        *(unsigned int*)&agg[obase + (size_t)oi * P4096] = u;
    }
}

// ---------------- kv[b,h,d,e] = sum_p relu(k_d)*v_e  (v_8 = 1) ----------------
__global__ __launch_bounds__(256) void kv_kernel(
    const ushort* __restrict__ qkv, const ushort* __restrict__ agg,
    float* __restrict__ kv)
{
    const int h = blockIdx.x, b = blockIdx.y, t = threadIdx.x;
    const ushort* src = (h < 32)
        ? qkv + ((size_t)(b * CQKV + h * 24)) * P4096
        : agg + ((size_t)(b * CQKV + (h - 32) * 24)) * P4096;

    float acc[72];
    #pragma unroll
    for (int i = 0; i < 72; i++) acc[i] = 0.0f;

    for (int pi = 0; pi < 16; pi++) {
        int p = t + pi * 256;
        float kvv[8], vv[8];
        #pragma unroll
        for (int d = 0; d < 8; d++) {
            float xk = bf2f(src[(size_t)(8 + d) * P4096 + p]);
            kvv[d] = xk > 0.0f ? xk : 0.0f;
        }
        #pragma unroll
        for (int e = 0; e < 8; e++) vv[e] = bf2f(src[(size_t)(16 + e) * P4096 + p]);
        #pragma unroll
        for (int d = 0; d < 8; d++) {
            #pragma unroll
            for (int e = 0; e < 8; e++) acc[d * 9 + e] += kvv[d] * vv[e];
            acc[d * 9 + 8] += kvv[d];
        }
    }

    #pragma unroll
    for (int i = 0; i < 72; i++) {
        float v = acc[i];
        #pragma unroll
        for (int off = 32; off > 0; off >>= 1) v += __shfl_xor(v, off, 64);
        acc[i] = v;
    }
    __shared__ float part[4][72];
    int wave = t >> 6, lane = t & 63;
    if (lane == 0) {
        #pragma unroll
        for (int i = 0; i < 72; i++) part[wave][i] = acc[i];
    }
    __syncthreads();
    if (t < 72)
        kv[((size_t)b * 64 + h) * 72 + t] = part[0][t] + part[1][t] + part[2][t] + part[3][t];
}

// ---------------- attn: out = (q.kv)_e / ((q.kv)_8 + 1e-15) ----------------
__global__ __launch_bounds__(256) void attn_out_kernel(
    const float* __restrict__ qplane, ushort* __restrict__ agg,
    const float* __restrict__ kv)
{
    const int pt = blockIdx.x, h = blockIdx.y, b = blockIdx.z, t = threadIdx.x;
    __shared__ float kvs[72];
    if (t < 72) kvs[t] = kv[((size_t)b * 64 + h) * 72 + t];
    __syncthreads();

    const bool lohead = (h < 32);
    const float* srcf = lohead
        ? qplane + ((size_t)(b * 256 + h * 8)) * P4096 : nullptr;
    const ushort* srcb = lohead ? nullptr
        : agg + ((size_t)(b * CQKV + (h - 32) * 24)) * P4096;

    int p = pt * 256 + t;
    float num[8]; float den = 0.0f;
    #pragma unroll
    for (int e = 0; e < 8; e++) num[e] = 0.0f;
    #pragma unroll
    for (int d = 0; d < 8; d++) {
        float q = lohead ? srcf[(size_t)d * P4096 + p]
                         : bf2f(srcb[(size_t)d * P4096 + p]);
        q = q > 0.0f ? q : 0.0f;
        #pragma unroll
        for (int e = 0; e < 8; e++) num[e] += q * kvs[d * 9 + e];
        den += q * kvs[d * 9 + 8];
    }
    float rd = 1.0f / (den + 1e-15f);
    ushort* dst = agg + ((size_t)(b * CQKV + (h / 2) * 24 + 8 + (h % 2) * 8)) * P4096 + p;
    #pragma unroll
    for (int e = 0; e < 8; e++)
        dst[(size_t)e * P4096] = f2bf(num[e] * rd);
}

// ---------------- GEMM3: y = W_proj(256x512) @ out[b](512x4096), bf16, BN ----------------
__global__ __launch_bounds__(256) void gemm_proj(
    const float* __restrict__ A,       // 256 x 512 fp32
    const ushort* __restrict__ Bagg,   // out in agg's k/v slots, map(k)=(k/16)*24+8+(k%16)
    float* __restrict__ Y,
    const float* __restrict__ bn_g, const float* __restrict__ bn_b,
    const float* __restrict__ bn_m, const float* __restrict__ bn_v)
{
    const int n0 = blockIdx.x * 64;
    const int m0 = blockIdx.y * 64;
    const int b  = blockIdx.z;
    const int t  = threadIdx.x;
    const int wave = t >> 6, lane = t & 63, quad = lane >> 4, l15 = lane & 15;

    __shared__ __align__(16) ushort As[64][40];
    __shared__ __align__(16) ushort Bs[64][40];

    f32x4 acc[4];
    #pragma unroll
    for (int nt = 0; nt < 4; nt++)
        #pragma unroll
        for (int r = 0; r < 4; r++) acc[nt][r] = 0.0f;

    const int am = t >> 2, ak = (t & 3) * 8;
    const int bn = t & 63, kg = (t >> 6) * 8;

    for (int k0 = 0; k0 < 512; k0 += 32) {
        float av[8];
        *(float4*)&av[0] = *(const float4*)(A + (size_t)(m0 + am) * 512 + k0 + ak);
        *(float4*)&av[4] = *(const float4*)(A + (size_t)(m0 + am) * 512 + k0 + ak + 4);
        ushort bu[8];
        #pragma unroll
        for (int i = 0; i < 8; i++) {
            int kk = k0 + kg + i;
            int amch = (kk >> 4) * 24 + 8 + (kk & 15);
            bu[i] = Bagg[((size_t)b * CQKV + amch) * P4096 + n0 + bn];
        }

        __syncthreads();
        stage_hi8(av, &As[am][ak]);
        {
            union { ushort us[8]; uint4 q; } Bp;
            #pragma unroll
            for (int i = 0; i < 8; i++) Bp.us[i] = bu[i];
            *(uint4*)&Bs[bn][kg] = Bp.q;
        }
        __syncthreads();

        bf16x8 af = *(const bf16x8*)&As[wave * 16 + l15][quad * 8];
        #pragma unroll
        for (int nt = 0; nt < 4; nt++) {
            bf16x8 bf = *(const bf16x8*)&Bs[nt * 16 + l15][quad * 8];
            acc[nt] = MFMA_BF16(af, bf, acc[nt], 0, 0, 0);
        }
    }

    #pragma unroll
    for (int nt = 0; nt < 4; nt++) {
        #pragma unroll
        for (int r = 0; r < 4; r++) {
            int row = m0 + wave * 16 + quad * 4 + r;
            int col = n0 + nt * 16 + l15;
            float inv = bn_g[row] / sqrtf(bn_v[row] + 1e-5f);
            float v = acc[nt][r] * inv + (bn_b[row] - bn_m[row] * inv);
            Y[((size_t)b * 256 + row) * P4096 + col] = v;
        }
    }
}

// ---------------- launch ----------------
extern "C" void kernel_launch(void* const* d_in, const int* in_sizes, int n_in,
                              void* d_out, int out_size, void* d_ws, size_t ws_size,
                              hipStream_t stream) {
    const float* x      = (const float*)d_in[0];
    const float* w_qkv  = (const float*)d_in[1];
    const float* w_dw   = (const float*)d_in[2];
    const float* w_pw   = (const float*)d_in[3];
    const float* w_proj = (const float*)d_in[4];
    const float* bn_g   = (const float*)d_in[5];
    const float* bn_b   = (const float*)d_in[6];
    const float* bn_m   = (const float*)d_in[7];
    const float* bn_v   = (const float*)d_in[8];
    float* y = (float*)d_out;

    char* ws = (char*)d_ws;
    ushort* qkv_bf = (ushort*)(ws);                  // 96 MiB: bf16 768ch
    float*  qplane = (float*) (ws + 100663296);      // 64 MiB: fp32 q (heads 0-31)
    ushort* agg_bf = (ushort*)(ws + 167772160);      // 96 MiB: agg; k/v slots reused for out
    // aliases inside agg region, dead once dwpw runs:
    ushort* XTh = (ushort*)(ws + 167772160);                       // 32 MiB
    ushort* XTl = (ushort*)(ws + 167772160 + 33554432);            // 32 MiB
    ushort* Awh = (ushort*)(ws + 167772160 + 67108864);            // 384 KiB
    ushort* Awl = (ushort*)(ws + 167772160 + 67108864 + 393216);   // 384 KiB
    float*  kvbuf  = (float*)d_out;                  // 288 KB scratch; gemm_proj overwrites

    conv_w<<<dim3(768), 128, 0, stream>>>(w_qkv, Awh, Awl);
    conv_x<<<dim3(64, 4, NB), 256, 0, stream>>>(x, XTh, XTl);

    gemm_fused<<<dim3(3072), 256, 0, stream>>>(
        Awh, Awl, XTh, XTl, qkv_bf, qplane);

    qfix_kernel<<<65536, 256, 0, stream>>>(qplane, w_qkv, x);

    dwpw_kernel<<<dim3(4, 96, NB), 512, 0, stream>>>(qkv_bf, w_dw, w_pw, agg_bf);

    kv_kernel<<<dim3(64, NB), 256, 0, stream>>>(qkv_bf, agg_bf, kvbuf);

    attn_out_kernel<<<dim3(16, 64, NB), 256, 0, stream>>>(qplane, agg_bf, kvbuf);

    gemm_proj<<<dim3(64, 4, NB), 256, 0, stream>>>(
        w_proj, agg_bf, y, bn_g, bn_b, bn_m, bn_v);
}

// Round 4
// 444.390 us; speedup vs baseline: 1.1326x; 1.0032x over previous
//
#include <hip/hip_runtime.h>
#include <hip/hip_bf16.h>

// LiteMSA pipeline, MI355X gfx950.
// B=16, Cin=256, Cqkv=768, H=W=64 (P=4096), heads=64 (24 ch: q8,k8,v8),
// out 512 ch -> proj 256 ch + BN. Output y fp32.
//
// GEMM1 (v5): pre-convert w_qkv and x to bf16 hi/lo ONCE (conv_w, conv_x),
// stored in virt-row order / transposed [p][c], pre-swizzled (16B slot ^=
// (row>>1)&3 per 64B window) so gemm_fused stages via global_load_lds w=16
// into linear LDS and reads frags with ~2-way (free) bank pattern.
// gemm_fused: 128x128 tile, 4 waves 2x2, acc 4x4; m-tiles 0-1 = q rows
// (3-term split bf16: hh+lh+hl), 2-5 = k/v rows (1-term).
// v5: TRUE pipeline — counted s_waitcnt vmcnt(8/4) + raw s_barrier pair per
// K-step (no __syncthreads vmcnt(0) drain; prefetched loads stay in flight
// across barriers, T3/T4 pattern). XCD-contiguous block swizzle kept.
// fp64 qfix for |q|<1e-4 unchanged.
//
// ws (256 MiB):
//   qkv_bf [0,96M)    bf16 768ch
//   qplane [96M,160M) fp32 256ch (q of heads 0-31)
//   agg_bf [160M,256M) bf16 768ch; ALIASED before dwpw by:
//     XTh [+0,32M) XTl [+32M,64M)  x^T bf16 hi/lo [b][4096][256] swizzled
//     Awh/Awl [+64M, +64.75M)      w_qkv bf16 hi/lo [768 virt][256] swizzled
//   (dwpw overwrites all of agg afterwards; attn reuses k/v slots)
// d_out: kvbuf 288K scratch at head; gemm_proj overwrites.

#define NB 16
#define CQKV 768
#define P4096 4096

typedef __bf16 bf16x8 __attribute__((ext_vector_type(8)));
typedef float f32x4 __attribute__((ext_vector_type(4)));

#define MFMA_BF16 __builtin_amdgcn_mfma_f32_16x16x32_bf16

__device__ __forceinline__ ushort f2bf(float f) {
    union { float f; unsigned int u; } x; x.f = f;
    unsigned int u = x.u;
    unsigned int r = (u + 0x7FFFu + ((u >> 16) & 1u)) >> 16;
    return (ushort)r;
}
__device__ __forceinline__ float bf2f(ushort u) {
    union { unsigned int u; float f; } x; x.u = ((unsigned int)u) << 16;
    return x.f;
}
__device__ __forceinline__ unsigned int pk2bf(float x, float y) {
    __hip_bfloat162 h = __float22bfloat162_rn(make_float2(x, y));  // v_cvt_pk_bf16_f32 (RNE)
    union { __hip_bfloat162 b; unsigned int u; } c; c.b = h; return c.u;
}
// 8 fp32 -> bf16 hi (one b128 LDS write)
__device__ __forceinline__ void stage_hi8(const float* v, ushort* dh) {
    union { unsigned int u[4]; uint4 q; } H;
    #pragma unroll
    for (int i = 0; i < 4; i++) H.u[i] = pk2bf(v[2 * i], v[2 * i + 1]);
    *(uint4*)dh = H.q;
}

__device__ __forceinline__ void gload16(void* lds, const void* g) {
    __builtin_amdgcn_global_load_lds(
        (const __attribute__((address_space(1))) void*)g,
        (__attribute__((address_space(3))) void*)lds, 16, 0, 0);
}

// ---------------- conv_w: w_qkv -> virt-row-ordered, swizzled bf16 hi/lo ----------------
// virt rows: 0..255 q (phys=(v>>3)*24+v&7), 256..767 kv (phys=(v2>>4)*24+8+v2&15).
// storage: row-major [768][256], within each 32-ushort (64B) window the 8-ushort
// chunk s goes to slot s ^ ((row>>1)&3).
__global__ __launch_bounds__(128) void conv_w(
    const float* __restrict__ W, ushort* __restrict__ Ah, ushort* __restrict__ Al)
{
    const int rv = blockIdx.x;     // 0..767
    const int t  = threadIdx.x;    // 0..127 -> c pair
    int phys;
    if (rv < 256) phys = (rv >> 3) * 24 + (rv & 7);
    else { int r2 = rv - 256; phys = (r2 >> 4) * 24 + 8 + (r2 & 15); }
    int c = t * 2;
    float w0 = W[(size_t)phys * 256 + c];
    float w1 = W[(size_t)phys * 256 + c + 1];
    unsigned int h = pk2bf(w0, w1);
    float f0 = __uint_as_float(h << 16);
    float f1 = __uint_as_float(h & 0xffff0000u);
    unsigned int l = pk2bf(w0 - f0, w1 - f1);
    int sl = ((c >> 3) & 3) ^ ((rv >> 1) & 3);
    int idx = (c & ~31) + sl * 8 + (c & 7);
    *(unsigned int*)&Ah[(size_t)rv * 256 + idx] = h;
    *(unsigned int*)&Al[(size_t)rv * 256 + idx] = l;
}

// ---------------- conv_x: x [b][256][4096] f32 -> XT hi/lo [b][4096][256] bf16, swizzled ----------------
__global__ __launch_bounds__(256) void conv_x(
    const float* __restrict__ X, ushort* __restrict__ XTh, ushort* __restrict__ XTl)
{
    const int pt = blockIdx.x;        // 0..63
    const int ct = blockIdx.y;        // 0..3
    const int b  = blockIdx.z;
    const int t  = threadIdx.x;
    const int p0 = pt * 64, c0 = ct * 64;

    __shared__ float tile[64][65];

    {
        int cr = t >> 2, pc = (t & 3) * 16;
        const float* xr = X + ((size_t)b * 256 + c0 + cr) * P4096 + p0 + pc;
        float4 v0 = *(const float4*)xr;
        float4 v1 = *(const float4*)(xr + 4);
        float4 v2 = *(const float4*)(xr + 8);
        float4 v3 = *(const float4*)(xr + 12);
        float* d = &tile[cr][pc];
        d[0]=v0.x; d[1]=v0.y; d[2]=v0.z; d[3]=v0.w;
        d[4]=v1.x; d[5]=v1.y; d[6]=v1.z; d[7]=v1.w;
        d[8]=v2.x; d[9]=v2.y; d[10]=v2.z; d[11]=v2.w;
        d[12]=v3.x; d[13]=v3.y; d[14]=v3.z; d[15]=v3.w;
    }
    __syncthreads();

    #pragma unroll
    for (int pass = 0; pass < 2; pass++) {
        int tp = t >> 2;
        int cc = (t & 3) + pass * 4;      // 0..7 chunk of 8 c
        int p  = p0 + tp;
        float v[8];
        #pragma unroll
        for (int j = 0; j < 8; j++) v[j] = tile[cc * 8 + j][tp];
        union { unsigned int u[4]; uint4 q; } H, L;
        #pragma unroll
        for (int i = 0; i < 4; i++) {
            unsigned int h = pk2bf(v[2 * i], v[2 * i + 1]);
            H.u[i] = h;
            float f0 = __uint_as_float(h << 16);
            float f1 = __uint_as_float(h & 0xffff0000u);
            L.u[i] = pk2bf(v[2 * i] - f0, v[2 * i + 1] - f1);
        }
        int c = c0 + cc * 8;
        int sl = ((c >> 3) & 3) ^ ((p >> 1) & 3);
        size_t idx = ((size_t)b * P4096 + p) * 256 + (c & ~31) + sl * 8;
        *(uint4*)&XTh[idx] = H.q;
        *(uint4*)&XTl[idx] = L.q;
    }
}

// ---------------- gemm_fused: all 768 virt rows; q tiles 3-term, kv tiles 1-term ----------------
// 128x128 tile, BK=32, 256 thr = 4 waves (2x2). Stage via global_load_lds w=16,
// double-buffered with COUNTED vmcnt: per K-step issue next-tile loads, then
// s_waitcnt vmcnt(8|4) (previous tile landed, new tile stays in flight),
// raw s_barrier, ds_read+MFMA, raw s_barrier (read-before-overwrite fence).
// LDS [128][32] ushort linear per buf; frag read slot = quad ^ ((row>>1)&3)
// (storage pre-swizzled to match). D: col=lane&15, row=quad*4+reg.
// Grid: 1-D 3072, XCD-contiguous swizzle lg=(hw&7)*384+(hw>>3) so the 6
// mt-blocks sharing a B-slice run on one XCD (B hits its L2).
__global__ __launch_bounds__(256, 2) void gemm_fused(
    const ushort* __restrict__ Ah, const ushort* __restrict__ Al,
    const ushort* __restrict__ Bh, const ushort* __restrict__ Bl,
    ushort* __restrict__ Cbf, float* __restrict__ qplane)
{
    const int hw = blockIdx.x;                 // 0..3071
    const int lg = (hw & 7) * 384 + (hw >> 3); // XCD-contiguous logical id
    const int mt = lg % 6;
    const int rem = lg / 6;                    // 0..511
    const int n0 = (rem & 31) * 128;
    const int b  = rem >> 5;
    const int t  = threadIdx.x;
    const int wave = t >> 6, lane = t & 63, quad = lane >> 4, l15 = lane & 15;
    const int wr = wave >> 1, wc = wave & 1;
    const int M0 = mt * 128;

    __shared__ __align__(16) ushort AsH[2][4096];
    __shared__ __align__(16) ushort AsL[2][4096];
    __shared__ __align__(16) ushort BsH[2][4096];
    __shared__ __align__(16) ushort BsL[2][4096];

    int aoff[4], boff[4];
    #pragma unroll
    for (int i = 0; i < 4; i++) {
        int ra = wr * 64 + i * 16 + l15;
        aoff[i] = ra * 64 + ((quad ^ ((ra >> 1) & 3)) << 4);
        int rb = wc * 64 + i * 16 + l15;
        boff[i] = rb * 64 + ((quad ^ ((rb >> 1) & 3)) << 4);
    }

    const int srow = t >> 2;               // 0..63
    const int schunk = (t & 3) * 8;        // ushort offset in 32-ushort window
    const size_t abase = (size_t)(M0 + srow) * 256 + schunk;
    const size_t bbase = ((size_t)b * P4096 + n0 + srow) * 256 + schunk;
    const int ldsoff = wave * 1024;        // bytes; +i*4096

    f32x4 acc[4][4];
    #pragma unroll
    for (int mi = 0; mi < 4; mi++)
        #pragma unroll
        for (int nj = 0; nj < 4; nj++)
            #pragma unroll
            for (int r = 0; r < 4; r++) acc[mi][nj][r] = 0.0f;

    if (mt < 2) {
        // ---- q rows: 3-term split; 8 global_load_lds per stage ----
        auto stageQ = [&](int d, int kw) {
            #pragma unroll
            for (int i = 0; i < 2; i++) {
                int lo = ldsoff + i * 4096;
                size_t so = (size_t)(i * 64) * 256 + (size_t)kw * 32;
                gload16((char*)AsH[d] + lo, Ah + abase + so);
                gload16((char*)AsL[d] + lo, Al + abase + so);
                gload16((char*)BsH[d] + lo, Bh + bbase + so);
                gload16((char*)BsL[d] + lo, Bl + bbase + so);
            }
        };
        stageQ(0, 0);
        for (int kw = 0; kw < 8; kw++) {
            int cur = kw & 1;
            if (kw < 7) {
                stageQ(cur ^ 1, kw + 1);
                asm volatile("s_waitcnt vmcnt(8)" ::: "memory");
            } else {
                asm volatile("s_waitcnt vmcnt(0)" ::: "memory");
            }
            __builtin_amdgcn_s_barrier();
            bf16x8 ah[4], al[4];
            #pragma unroll
            for (int mi = 0; mi < 4; mi++) {
                ah[mi] = *(const bf16x8*)((const char*)AsH[cur] + aoff[mi]);
                al[mi] = *(const bf16x8*)((const char*)AsL[cur] + aoff[mi]);
            }
            #pragma unroll
            for (int nj = 0; nj < 4; nj++) {
                bf16x8 bh = *(const bf16x8*)((const char*)BsH[cur] + boff[nj]);
                bf16x8 bl = *(const bf16x8*)((const char*)BsL[cur] + boff[nj]);
                #pragma unroll
                for (int mi = 0; mi < 4; mi++) {
                    acc[mi][nj] = MFMA_BF16(ah[mi], bh, acc[mi][nj], 0, 0, 0);
                    acc[mi][nj] = MFMA_BF16(al[mi], bh, acc[mi][nj], 0, 0, 0);
                    acc[mi][nj] = MFMA_BF16(ah[mi], bl, acc[mi][nj], 0, 0, 0);
                }
            }
            __builtin_amdgcn_s_barrier();   // reads of buf[cur] done before next overwrite
        }
        #pragma unroll
        for (int mi = 0; mi < 4; mi++)
            #pragma unroll
            for (int nj = 0; nj < 4; nj++)
                #pragma unroll
                for (int r = 0; r < 4; r++) {
                    int rv = M0 + wr * 64 + mi * 16 + quad * 4 + r;
                    int rp = (rv >> 3) * 24 + (rv & 7);
                    int col = n0 + wc * 64 + nj * 16 + l15;
                    float v = acc[mi][nj][r];
                    Cbf[((size_t)b * CQKV + rp) * P4096 + col] = f2bf(v);
                    qplane[((size_t)b * 256 + rv) * P4096 + col] = v;
                }
    } else {
        // ---- k/v rows: single term; 4 global_load_lds per stage ----
        auto stageKV = [&](int d, int kw) {
            #pragma unroll
            for (int i = 0; i < 2; i++) {
                int lo = ldsoff + i * 4096;
                size_t so = (size_t)(i * 64) * 256 + (size_t)kw * 32;
                gload16((char*)AsH[d] + lo, Ah + abase + so);
                gload16((char*)BsH[d] + lo, Bh + bbase + so);
            }
        };
        stageKV(0, 0);
        for (int kw = 0; kw < 8; kw++) {
            int cur = kw & 1;
            if (kw < 7) {
                stageKV(cur ^ 1, kw + 1);
                asm volatile("s_waitcnt vmcnt(4)" ::: "memory");
            } else {
                asm volatile("s_waitcnt vmcnt(0)" ::: "memory");
            }
            __builtin_amdgcn_s_barrier();
            bf16x8 ah[4];
            #pragma unroll
            for (int mi = 0; mi < 4; mi++)
                ah[mi] = *(const bf16x8*)((const char*)AsH[cur] + aoff[mi]);
            #pragma unroll
            for (int nj = 0; nj < 4; nj++) {
                bf16x8 bh = *(const bf16x8*)((const char*)BsH[cur] + boff[nj]);
                #pragma unroll
                for (int mi = 0; mi < 4; mi++)
                    acc[mi][nj] = MFMA_BF16(ah[mi], bh, acc[mi][nj], 0, 0, 0);
            }
            __builtin_amdgcn_s_barrier();
        }
        #pragma unroll
        for (int mi = 0; mi < 4; mi++)
            #pragma unroll
            for (int nj = 0; nj < 4; nj++)
                #pragma unroll
                for (int r = 0; r < 4; r++) {
                    int rv2 = (M0 - 256) + wr * 64 + mi * 16 + quad * 4 + r;
                    int rp = (rv2 >> 4) * 24 + 8 + (rv2 & 15);
                    int col = n0 + wc * 64 + nj * 16 + l15;
                    Cbf[((size_t)b * CQKV + rp) * P4096 + col] = f2bf(acc[mi][nj][r]);
                }
    }
}

// ---------------- qfix: recompute |q|<1e-4 in fp64 (kills relu sign flips) ----------------
__global__ __launch_bounds__(256) void qfix_kernel(
    float* __restrict__ qplane, const float* __restrict__ w_qkv,
    const float* __restrict__ x)
{
    size_t i = (size_t)blockIdx.x * 256 + threadIdx.x;  // over 16*256*4096
    float q = qplane[i];
    if (fabsf(q) >= 1e-4f) return;
    int p   = (int)(i & 4095);
    int qch = (int)((i >> 12) & 255);
    int b   = (int)(i >> 20);
    int row = (qch >> 3) * 24 + (qch & 7);
    const float* wr = w_qkv + (size_t)row * 256;
    const float* xr = x + (size_t)b * 256 * P4096 + p;
    double s = 0.0;
    for (int c = 0; c < 256; c++)
        s += (double)wr[c] * (double)xr[(size_t)c * P4096];
    qplane[i] = (float)s;
}

// ---------------- dw 3x3 + grouped pw (bf16; feeds only heads 32-63) ----------------
// 512 thr, 16-row tiles, bf16 LDS (23 KB, 8-wave blocks -> 32 waves/CU),
// 2 adjacent px/thread sharing the 4-value tap window, weights via uniform
// scalar (SGPR) loads, packed uint stores.
__global__ __launch_bounds__(512, 8) void dwpw_kernel(
    const ushort* __restrict__ qkv, const float* __restrict__ wdw,
    const float* __restrict__ wpw, ushort* __restrict__ agg)
{
    const int rt = blockIdx.x;    // 0..3 (16 output rows each)
    const int g  = blockIdx.y;    // 0..95
    const int b  = blockIdx.z;
    const int t  = threadIdx.x;   // 0..511
    const int r0 = rt * 16;
    const int cg = g * 8;

    __shared__ __align__(16) ushort tile[8][18][80];   // 23040 B

    const ushort* src = qkv + ((size_t)(b * CQKV + cg)) * P4096;

    if (t < 288) {
        int ch = t / 36;
        int rr = (t % 36) >> 1;
        int side = t & 1;
        *(uint4*)&tile[ch][rr][side * 72] = make_uint4(0, 0, 0, 0);
    }
    #pragma unroll
    for (int i = 0; i < 3; i++) {
        int id = t + i * 512;
        if (id < 1152) {
            int ch  = id / 144;
            int rem = id - ch * 144;
            int rr  = rem >> 3;
            int oct = (rem & 7) * 8;
            int grow = r0 - 1 + rr;
            uint4 v = make_uint4(0, 0, 0, 0);
            if (grow >= 0 && grow < 64)
                v = *(const uint4*)(src + (size_t)ch * P4096 + (size_t)grow * 64 + oct);
            *(uint4*)&tile[ch][rr][8 + oct] = v;
        }
    }
    __syncthreads();

    const int kc  = t & 31;        // col pair: cols 2kc, 2kc+1
    const int row = t >> 5;        // 0..15
    const float* wdwg = wdw + (size_t)cg * 9;   // block-uniform -> s_load
    const float* wpwg = wpw + (size_t)cg * 8;

    float acc0[8], acc1[8];
    #pragma unroll
    for (int oi = 0; oi < 8; oi++) { acc0[oi] = 0.0f; acc1[oi] = 0.0f; }

    #pragma unroll
    for (int c = 0; c < 8; c++) {
        float dv0 = 0.0f, dv1 = 0.0f;
        #pragma unroll
        for (int dy = 0; dy < 3; dy++) {
            const ushort* rp = &tile[c][row + dy][2 * kc + 4];
            unsigned int u1 = *(const unsigned int*)(rp + 2);
            unsigned int u2 = *(const unsigned int*)(rp + 4);
            unsigned int u3 = *(const unsigned int*)(rp + 6);
            float xm1 = __uint_as_float(u1 & 0xffff0000u);
            float x0  = __uint_as_float(u2 << 16);
            float x1  = __uint_as_float(u2 & 0xffff0000u);
            float x2  = __uint_as_float(u3 << 16);
            float w0 = wdwg[c * 9 + dy * 3 + 0];
            float w1 = wdwg[c * 9 + dy * 3 + 1];
            float w2 = wdwg[c * 9 + dy * 3 + 2];
            dv0 = fmaf(w0, xm1, dv0); dv0 = fmaf(w1, x0, dv0); dv0 = fmaf(w2, x1, dv0);
            dv1 = fmaf(w0, x0,  dv1); dv1 = fmaf(w1, x1, dv1); dv1 = fmaf(w2, x2, dv1);
        }
        #pragma unroll
        for (int oi = 0; oi < 8; oi++) {
            float w = wpwg[oi * 8 + c];
            acc0[oi] = fmaf(w, dv0, acc0[oi]);
            acc1[oi] = fmaf(w, dv1, acc1[oi]);
        }
    }

    size_t obase = ((size_t)(b * CQKV + cg)) * P4096 + (size_t)(r0 + row) * 64 + 2 * kc;
    #pragma unroll
    for (int oi = 0; oi < 8; oi++) {
        unsigned int u = (unsigned int)f2bf(acc0[oi]) |
                         ((unsigned int)f2bf(acc1[oi]) << 16);
        *(unsigned int*)&agg[obase + (size_t)oi * P4096] = u;
    }
}

// ---------------- kv[b,h,d,e] = sum_p relu(k_d)*v_e  (v_8 = 1) ----------------
__global__ __launch_bounds__(256) void kv_kernel(
    const ushort* __restrict__ qkv, const ushort* __restrict__ agg,
    float* __restrict__ kv)
{
    const int h = blockIdx.x, b = blockIdx.y, t = threadIdx.x;
    const ushort* src = (h < 32)
        ? qkv + ((size_t)(b * CQKV + h * 24)) * P4096
        : agg + ((size_t)(b * CQKV + (h - 32) * 24)) * P4096;

    float acc[72];
    #pragma unroll
    for (int i = 0; i < 72; i++) acc[i] = 0.0f;

    for (int pi = 0; pi < 16; pi++) {
        int p = t + pi * 256;
        float kvv[8], vv[8];
        #pragma unroll
        for (int d = 0; d < 8; d++) {
            float xk = bf2f(src[(size_t)(8 + d) * P4096 + p]);
            kvv[d] = xk > 0.0f ? xk : 0.0f;
        }
        #pragma unroll
        for (int e = 0; e < 8; e++) vv[e] = bf2f(src[(size_t)(16 + e) * P4096 + p]);
        #pragma unroll
        for (int d = 0; d < 8; d++) {
            #pragma unroll
            for (int e = 0; e < 8; e++) acc[d * 9 + e] += kvv[d] * vv[e];
            acc[d * 9 + 8] += kvv[d];
        }
    }

    #pragma unroll
    for (int i = 0; i < 72; i++) {
        float v = acc[i];
        #pragma unroll
        for (int off = 32; off > 0; off >>= 1) v += __shfl_xor(v, off, 64);
        acc[i] = v;
    }
    __shared__ float part[4][72];
    int wave = t >> 6, lane = t & 63;
    if (lane == 0) {
        #pragma unroll
        for (int i = 0; i < 72; i++) part[wave][i] = acc[i];
    }
    __syncthreads();
    if (t < 72)
        kv[((size_t)b * 64 + h) * 72 + t] = part[0][t] + part[1][t] + part[2][t] + part[3][t];
}

// ---------------- attn: out = (q.kv)_e / ((q.kv)_8 + 1e-15) ----------------
__global__ __launch_bounds__(256) void attn_out_kernel(
    const float* __restrict__ qplane, ushort* __restrict__ agg,
    const float* __restrict__ kv)
{
    const int pt = blockIdx.x, h = blockIdx.y, b = blockIdx.z, t = threadIdx.x;
    __shared__ float kvs[72];
    if (t < 72) kvs[t] = kv[((size_t)b * 64 + h) * 72 + t];
    __syncthreads();

    const bool lohead = (h < 32);
    const float* srcf = lohead
        ? qplane + ((size_t)(b * 256 + h * 8)) * P4096 : nullptr;
    const ushort* srcb = lohead ? nullptr
        : agg + ((size_t)(b * CQKV + (h - 32) * 24)) * P4096;

    int p = pt * 256 + t;
    float num[8]; float den = 0.0f;
    #pragma unroll
    for (int e = 0; e < 8; e++) num[e] = 0.0f;
    #pragma unroll
    for (int d = 0; d < 8; d++) {
        float q = lohead ? srcf[(size_t)d * P4096 + p]
                         : bf2f(srcb[(size_t)d * P4096 + p]);
        q = q > 0.0f ? q : 0.0f;
        #pragma unroll
        for (int e = 0; e < 8; e++) num[e] += q * kvs[d * 9 + e];
        den += q * kvs[d * 9 + 8];
    }
    float rd = 1.0f / (den + 1e-15f);
    ushort* dst = agg + ((size_t)(b * CQKV + (h / 2) * 24 + 8 + (h % 2) * 8)) * P4096 + p;
    #pragma unroll
    for (int e = 0; e < 8; e++)
        dst[(size_t)e * P4096] = f2bf(num[e] * rd);
}

// ---------------- GEMM3: y = W_proj(256x512) @ out[b](512x4096), bf16, BN ----------------
__global__ __launch_bounds__(256) void gemm_proj(
    const float* __restrict__ A,       // 256 x 512 fp32
    const ushort* __restrict__ Bagg,   // out in agg's k/v slots, map(k)=(k/16)*24+8+(k%16)
    float* __restrict__ Y,
    const float* __restrict__ bn_g, const float* __restrict__ bn_b,
    const float* __restrict__ bn_m, const float* __restrict__ bn_v)
{
    const int n0 = blockIdx.x * 64;
    const int m0 = blockIdx.y * 64;
    const int b  = blockIdx.z;
    const int t  = threadIdx.x;
    const int wave = t >> 6, lane = t & 63, quad = lane >> 4, l15 = lane & 15;

    __shared__ __align__(16) ushort As[64][40];
    __shared__ __align__(16) ushort Bs[64][40];

    f32x4 acc[4];
    #pragma unroll
    for (int nt = 0; nt < 4; nt++)
        #pragma unroll
        for (int r = 0; r < 4; r++) acc[nt][r] = 0.0f;

    const int am = t >> 2, ak = (t & 3) * 8;
    const int bn = t & 63, kg = (t >> 6) * 8;

    for (int k0 = 0; k0 < 512; k0 += 32) {
        float av[8];
        *(float4*)&av[0] = *(const float4*)(A + (size_t)(m0 + am) * 512 + k0 + ak);
        *(float4*)&av[4] = *(const float4*)(A + (size_t)(m0 + am) * 512 + k0 + ak + 4);
        ushort bu[8];
        #pragma unroll
        for (int i = 0; i < 8; i++) {
            int kk = k0 + kg + i;
            int amch = (kk >> 4) * 24 + 8 + (kk & 15);
            bu[i] = Bagg[((size_t)b * CQKV + amch) * P4096 + n0 + bn];
        }

        __syncthreads();
        stage_hi8(av, &As[am][ak]);
        {
            union { ushort us[8]; uint4 q; } Bp;
            #pragma unroll
            for (int i = 0; i < 8; i++) Bp.us[i] = bu[i];
            *(uint4*)&Bs[bn][kg] = Bp.q;
        }
        __syncthreads();

        bf16x8 af = *(const bf16x8*)&As[wave * 16 + l15][quad * 8];
        #pragma unroll
        for (int nt = 0; nt < 4; nt++) {
            bf16x8 bf = *(const bf16x8*)&Bs[nt * 16 + l15][quad * 8];
            acc[nt] = MFMA_BF16(af, bf, acc[nt], 0, 0, 0);
        }
    }

    #pragma unroll
    for (int nt = 0; nt < 4; nt++) {
        #pragma unroll
        for (int r = 0; r < 4; r++) {
            int row = m0 + wave * 16 + quad * 4 + r;
            int col = n0 + nt * 16 + l15;
            float inv = bn_g[row] / sqrtf(bn_v[row] + 1e-5f);
            float v = acc[nt][r] * inv + (bn_b[row] - bn_m[row] * inv);
            Y[((size_t)b * 256 + row) * P4096 + col] = v;
        }
    }
}

// ---------------- launch ----------------
extern "C" void kernel_launch(void* const* d_in, const int* in_sizes, int n_in,
                              void* d_out, int out_size, void* d_ws, size_t ws_size,
                              hipStream_t stream) {
    const float* x      = (const float*)d_in[0];
    const float* w_qkv  = (const float*)d_in[1];
    const float* w_dw   = (const float*)d_in[2];
    const float* w_pw   = (const float*)d_in[3];
    const float* w_proj = (const float*)d_in[4];
    const float* bn_g   = (const float*)d_in[5];
    const float* bn_b   = (const float*)d_in[6];
    const float* bn_m   = (const float*)d_in[7];
    const float* bn_v   = (const float*)d_in[8];
    float* y = (float*)d_out;

    char* ws = (char*)d_ws;
    ushort* qkv_bf = (ushort*)(ws);                  // 96 MiB: bf16 768ch
    float*  qplane = (float*) (ws + 100663296);      // 64 MiB: fp32 q (heads 0-31)
    ushort* agg_bf = (ushort*)(ws + 167772160);      // 96 MiB: agg; k/v slots reused for out
    // aliases inside agg region, dead once dwpw runs:
    ushort* XTh = (ushort*)(ws + 167772160);                       // 32 MiB
    ushort* XTl = (ushort*)(ws + 167772160 + 33554432);            // 32 MiB
    ushort* Awh = (ushort*)(ws + 167772160 + 67108864);            // 384 KiB
    ushort* Awl = (ushort*)(ws + 167772160 + 67108864 + 393216);   // 384 KiB
    float*  kvbuf  = (float*)d_out;                  // 288 KB scratch; gemm_proj overwrites

    conv_w<<<dim3(768), 128, 0, stream>>>(w_qkv, Awh, Awl);
    conv_x<<<dim3(64, 4, NB), 256, 0, stream>>>(x, XTh, XTl);

    gemm_fused<<<dim3(3072), 256, 0, stream>>>(
        Awh, Awl, XTh, XTl, qkv_bf, qplane);

    qfix_kernel<<<65536, 256, 0, stream>>>(qplane, w_qkv, x);

    dwpw_kernel<<<dim3(4, 96, NB), 512, 0, stream>>>(qkv_bf, w_dw, w_pw, agg_bf);

    kv_kernel<<<dim3(64, NB), 256, 0, stream>>>(qkv_bf, agg_bf, kvbuf);

    attn_out_kernel<<<dim3(16, 64, NB), 256, 0, stream>>>(qplane, agg_bf, kvbuf);

    gemm_proj<<<dim3(64, 4, NB), 256, 0, stream>>>(
        w_proj, agg_bf, y, bn_g, bn_b, bn_m, bn_v);
}